// Round 2
// 642.165 us; speedup vs baseline: 1.2012x; 1.2012x over previous
//
#include <hip/hip_runtime.h>
#include <hip/hip_bf16.h>
#include <stdint.h>

typedef __hip_bfloat16 bf16;
typedef _Float16 half_t;
typedef _Float16 half8 __attribute__((ext_vector_type(8)));
typedef float f32x4 __attribute__((ext_vector_type(4)));

#define BVOXN 23328   // B * 729, B = 32 (fixed by setup_inputs)

__device__ __forceinline__ float b2f(bf16 v) { return __bfloat162float(v); }

// ---- workspace layout (float offsets) -------------------------------------
#define OFF_L0W   64        // 192    lin0_w f32
#define OFF_B0    256       // 64     lin0_b
#define OFF_W0    320       // 5184   conv0_w transposed [i][tap][o]
#define OFF_CB0   5504      // 64     conv0_b
#define OFF_L1W   5568      // 4096   lin1_w
#define OFF_B1    9664      // 64     lin1_b
#define OFF_W1T   9728      // 110592 conv1_w f32 (legacy k_convert output, unused)
#define OFF_CB1   120320    // 64     conv1_b
#define OFF_LFW   120384    // 192    linf_w
#define OFF_BF    120576    // 64     linf_b
#define OFF_SUMS  120640    // 93312  u64[46656]: packed per-cluster sums (zeroed)
#define OFF_GA0   213952    // 69984  conv0 input grid f32 (zeroed)
#define OFF_GT    283936    // 746496 slots = half[1492992] conv-frame grid1 (zeroed)
#define OFF_C0T   1030432   // 746496 slots = half[1492992] conv0oT[v_raw][k] (raw)
#define OFF_WT    1776928   // 57344  slots = half[114688] Wt[28][o][i]; tap27 = L1^T
#define OFF_WC    1834272   // 192    folded point matrix
#define OFF_BVEC  1834464   // 64     folded bias
#define OFF_G     1834528   // 746496 slots = bf16[1492992] voxel table G[v_raw][c]
// end = 2581024 f32 = 10.3 MB

// fixed-point packing for cluster sums: e = round(v*2^20) + 2^23 (always >0)
#define FP_SCALE 1048576.0f
#define FP_BIAS  8388608

// ---------------------------------------------------------------------------
// Decide whether float inputs are f32 (flag=1) or bf16 (flag=0).
__global__ void k_probe(const void* lin1_w, int* flag) {
    __shared__ int cnt[256];
    int t = threadIdx.x;
    const bf16* p = (const bf16*)lin1_w;
    int c = 0;
    for (int j = t; j < 2048; j += 256) {
        float v = b2f(p[2 * j]);
        if (!(v == v) || fabsf(v) > 64.0f || (v != 0.0f && fabsf(v) < 1e-20f)) c++;
    }
    cnt[t] = c;
    __syncthreads();
    for (int s = 128; s > 0; s >>= 1) {
        if (t < s) cnt[t] += cnt[t + s];
        __syncthreads();
    }
    if (t == 0) *flag = (cnt[0] > 100) ? 1 : 0;
}

__device__ __forceinline__ float ldf(const void* p, int j, int isf) {
    return isf ? ((const float*)p)[j] : b2f(((const bf16*)p)[j]);
}

// Convert all 10 weight arrays into canonical f32 ws copies (convs transposed).
__global__ void k_convert(const void* l0w, const void* l0b, const void* w0,
                          const void* cb0, const void* l1w, const void* l1b,
                          const void* w1, const void* cb1, const void* lfw,
                          const void* lfb, const int* flag, float* ws) {
    int t = blockIdx.x * 256 + threadIdx.x;
    if (t >= 120576) return;
    int isf = *flag;
    const void* src;
    int j;
    float* dst;
    if (t < 192)        { src = l0w; j = t;          dst = ws + OFF_L0W + j; }
    else if (t < 256)   { src = l0b; j = t - 192;    dst = ws + OFF_B0  + j; }
    else if (t < 5440)  {
        j = t - 256;                        // conv0_w [o][i][tap] -> [i][tap][o]
        int o = j / 81, r = j % 81, i = r / 27, tap = r % 27;
        src = w0;
        dst = ws + OFF_W0 + (i * 27 + tap) * 64 + o;
    }
    else if (t < 5504)  { src = cb0; j = t - 5440;   dst = ws + OFF_CB0 + j; }
    else if (t < 9600)  { src = l1w; j = t - 5504;   dst = ws + OFF_L1W + j; }
    else if (t < 9664)  { src = l1b; j = t - 9600;   dst = ws + OFF_B1  + j; }
    else if (t < 120256) {
        j = t - 9664;                       // conv1_w [o][i][tap] -> [i][tap][o]
        int o = j / 1728, r = j % 1728, i = r / 27, tap = r % 27;
        src = w1;
        dst = ws + OFF_W1T + (i * 27 + tap) * 64 + o;
    }
    else if (t < 120320) { src = cb1; j = t - 120256; dst = ws + OFF_CB1 + j; }
    else if (t < 120512) { src = lfw; j = t - 120320; dst = ws + OFF_LFW + j; }
    else                 { src = lfb; j = t - 120512; dst = ws + OFF_BF  + j; }
    *dst = ldf(src, j, isf);
}

// MFMA weights: Wt[tap][o][i] f16. taps 0..26 = conv1_w; tap 27 = lin1_w^T
// (used by k_G2 as the B operand of the lin1 term of G).
__global__ void k_wprep(const void* w1, const void* l1w, const int* flag,
                        half_t* Wt) {
    int t = blockIdx.x * 256 + threadIdx.x;
    if (t >= 28 * 4096) return;
    int isf = *flag;
    int tap = t >> 12;
    int r = t & 4095;
    int o = r >> 6, i = r & 63;
    float v;
    if (tap < 27) v = ldf(w1, (o * 64 + i) * 27 + tap, isf);   // [o][i][tap]
    else          v = ldf(l1w, i * 64 + o, isf);               // l1w[k][c] -> [c][k]
    Wt[t] = (half_t)v;
}

// Fold: Wc = lin0_w@lin1_w + linf_w [3,64]; bvec = lin0_b@lin1_w + lin1_b + linf_b
__global__ void k_prep(const float* ws, float* Wc, float* bvec) {
    const float* l0w = ws + OFF_L0W;
    const float* l0b = ws + OFF_B0;
    const float* l1w = ws + OFF_L1W;
    const float* l1b = ws + OFF_B1;
    const float* lfw = ws + OFF_LFW;
    const float* lfb = ws + OFF_BF;
    int c = threadIdx.x;
    float bv = l1b[c] + lfb[c];
    for (int k = 0; k < 64; ++k) bv += l0b[k] * l1w[k * 64 + c];
    bvec[c] = bv;
    for (int r = 0; r < 3; ++r) {
        float wv = lfw[r * 64 + c];
        for (int k = 0; k < 64; ++k) wv += l0w[r * 64 + k] * l1w[k * 64 + c];
        Wc[r * 64 + c] = wv;
    }
}

// Per-cluster sums of x (3 ch) + counts: 2 packed u64 atomics per point.
__global__ void k_accum(const void* x, const int* consec, const int* flag,
                        unsigned long long* sums8, int N) {
    int i = blockIdx.x * 256 + threadIdx.x;
    if (i >= N) return;
    int isf = *flag;
    int u = consec[i];
    float v0 = ldf(x, 3 * i + 0, isf);
    float v1 = ldf(x, 3 * i + 1, isf);
    float v2 = ldf(x, 3 * i + 2, isf);
    unsigned e0 = (unsigned)(__float2int_rn(v0 * FP_SCALE) + FP_BIAS);
    unsigned e1 = (unsigned)(__float2int_rn(v1 * FP_SCALE) + FP_BIAS);
    unsigned e2 = (unsigned)(__float2int_rn(v2 * FP_SCALE) + FP_BIAS);
    atomicAdd(&sums8[2 * u + 0], ((unsigned long long)e0 << 32) | e1);
    atomicAdd(&sums8[2 * u + 1], (1ull << 32) | e2);
}

__device__ __forceinline__ void decode_mean(const unsigned long long* sums8, int u,
                                            float& m0, float& m1, float& m2) {
    unsigned long long S1 = sums8[2 * u + 0];
    unsigned long long S2 = sums8[2 * u + 1];
    double n = (double)(unsigned)(S2 >> 32);
    double k = 1.0 / (1048576.0 * n);
    double nb = n * 8388608.0;
    m0 = (float)(((double)(unsigned)(S1 >> 32) - nb) * k);
    m1 = (float)(((double)(unsigned)(S1 & 0xffffffffu) - nb) * k);
    m2 = (float)(((double)(unsigned)(S2 & 0xffffffffu) - nb) * k);
}

// Scatter means into conv0 input grid (flat [3, BVOXN] raw-viewed as (B,3,9,9,9))
__global__ void k_scatter0(const unsigned long long* sums8, const int* unc,
                           float* gridA0, int U) {
    int u = blockIdx.x * 256 + threadIdx.x;
    if (u >= U) return;
    int v = unc[u];
    float m0, m1, m2;
    decode_mean(sums8, u, m0, m1, m2);
    gridA0[0 * BVOXN + v] = m0;
    gridA0[1 * BVOXN + v] = m1;
    gridA0[2 * BVOXN + v] = m2;
}

// conv0: conv-frame (B,3,9,9,9)->(B,64,9,9,9), 3x3x3 pad 1, + bias.
// Output stored in RAW voxel-major layout conv0oT[v_raw][k_raw]:
// conv-frame (b,o,pos) lives at raw flat (b*64+o)*729+pos, i.e.
// k_raw = 2b + (o>>5), v_raw = (o&31)*729 + pos  (reference raw-view semantics).
__global__ __launch_bounds__(256) void k_conv0s(const float* gridA0, const float* w0t,
                                                const float* cb0, half_t* conv0oT) {
    __shared__ float slab[3 * 363];
    int b = blockIdx.x / 9, d = blockIdx.x % 9;
    int t = threadIdx.x;
    for (int s = t; s < 3 * 363; s += 256) {
        int i = s / 363, rr = s % 363;
        int zz = rr / 121, p = rr % 121;
        int ph = p / 11, pw = p % 11;
        int z = d + zz - 1, hh = ph - 1, ww = pw - 1;
        float v = 0.0f;
        if ((unsigned)z < 9u && (unsigned)hh < 9u && (unsigned)ww < 9u)
            v = gridA0[b * 2187 + i * 729 + z * 81 + hh * 9 + ww];
        slab[s] = v;
    }
    __syncthreads();

    int og = t >> 5, l = t & 31;
    int hw[3], hj[3], wj[3];
    bool valid[3];
    #pragma unroll
    for (int j = 0; j < 3; ++j) {
        int q = l + 32 * j;
        valid[j] = q < 81;
        int qc = q < 81 ? q : 80;
        hw[j] = q; hj[j] = qc / 9; wj[j] = qc % 9;
    }
    float acc[8][3];
    #pragma unroll
    for (int oj = 0; oj < 8; ++oj) {
        float bv = cb0[og * 8 + oj];
        acc[oj][0] = bv; acc[oj][1] = bv; acc[oj][2] = bv;
    }

    for (int i = 0; i < 3; ++i) {
        const float* sb = slab + i * 363;
        const float* wb = w0t + (i * 27) * 64 + og * 8;
        for (int kd = 0; kd < 3; ++kd)
            for (int kh = 0; kh < 3; ++kh) {
                int ib0 = kd * 121 + (hj[0] + kh) * 11 + wj[0];
                int ib1 = kd * 121 + (hj[1] + kh) * 11 + wj[1];
                int ib2 = kd * 121 + (hj[2] + kh) * 11 + wj[2];
                #pragma unroll
                for (int kw = 0; kw < 3; ++kw) {
                    int tap = kd * 9 + kh * 3 + kw;
                    const float4* w4 = reinterpret_cast<const float4*>(wb + tap * 64);
                    float4 wA = w4[0];
                    float4 wB = w4[1];
                    float in0 = sb[ib0 + kw];
                    float in1 = sb[ib1 + kw];
                    float in2 = sb[ib2 + kw];
                    acc[0][0] += wA.x * in0; acc[0][1] += wA.x * in1; acc[0][2] += wA.x * in2;
                    acc[1][0] += wA.y * in0; acc[1][1] += wA.y * in1; acc[1][2] += wA.y * in2;
                    acc[2][0] += wA.z * in0; acc[2][1] += wA.z * in1; acc[2][2] += wA.z * in2;
                    acc[3][0] += wA.w * in0; acc[3][1] += wA.w * in1; acc[3][2] += wA.w * in2;
                    acc[4][0] += wB.x * in0; acc[4][1] += wB.x * in1; acc[4][2] += wB.x * in2;
                    acc[5][0] += wB.y * in0; acc[5][1] += wB.y * in1; acc[5][2] += wB.y * in2;
                    acc[6][0] += wB.z * in0; acc[6][1] += wB.z * in1; acc[6][2] += wB.z * in2;
                    acc[7][0] += wB.w * in0; acc[7][1] += wB.w * in1; acc[7][2] += wB.w * in2;
                }
            }
    }

    #pragma unroll
    for (int oj = 0; oj < 8; ++oj) {
        int o = og * 8 + oj;
        int kraw = 2 * b + (o >> 5);
        int bvr = o & 31;
        #pragma unroll
        for (int j = 0; j < 3; ++j)
            if (valid[j])
                conv0oT[(bvr * 729 + d * 81 + hw[j]) * 64 + kraw] =
                    (half_t)acc[oj][j];
    }
}

// conv1 input: raw grid1[c][v] = mean@l0w + l0b + conv0o_raw[c][v] at covered v.
// Written into the CONV-FRAME voxel-major buffer gridTc[(b'*729+pos)*64 + ch']
// with b' = c>>1, ch' = (c&1)*32 + (v/729)  (raw-view reshape semantics).
__global__ void k_scatter1(const unsigned long long* sums8, const int* unc,
                           const half_t* conv0oT, const float* l0w, const float* l0b,
                           half_t* gridTc) {
    int u = blockIdx.x;
    int c = threadIdx.x;
    int v = unc[u];
    int bvr = v / 729, pos = v % 729;
    float m0, m1, m2;
    decode_mean(sums8, u, m0, m1, m2);
    float val = l0b[c] + m0 * l0w[c] + m1 * l0w[64 + c] + m2 * l0w[128 + c] +
                (float)conv0oT[v * 64 + c];
    gridTc[((c >> 1) * 729 + pos) * 64 + ((c & 1) * 32 + bvr)] = (half_t)val;
}

// conv1 via MFMA in the conv frame. Per block: one (b', z, N-half).
// M = 81 spatial (pad 96) over 6 waves, K = 27 taps x 64 ch, N = 32 outputs.
// Epilogue maps conv-frame (b', o', pos) to raw G[(o'&31)*729+pos][2b'+nh].
// LDS slab row stride 72 halfs (144 B): 4 banks mod 32 -> 2-way alias only (free).
__global__ __launch_bounds__(384) void k_conv1m(const half_t* __restrict__ gridTc,
                                                const half_t* __restrict__ Wt,
                                                const float* __restrict__ cb1,
                                                bf16* __restrict__ G) {
    __shared__ __align__(16) half_t slab[363 * 72];
    int bid = blockIdx.x;
    int nh = bid & 1;
    int t2 = bid >> 1;
    int b = t2 / 9, z = t2 % 9;
    int tid = threadIdx.x;

    // stage 3x11x11 halo window (conv-frame), channel-contiguous, zero-padded
    for (int s = tid; s < 2904; s += 384) {
        int pos = s >> 3, ic = s & 7;
        int zz = pos / 121, rr = pos % 121;
        int ph = rr / 11, pw = rr % 11;
        int zi = z + zz - 1, yi = ph - 1, xi = pw - 1;
        half8 v;
        #pragma unroll
        for (int j = 0; j < 8; ++j) v[j] = (half_t)0.f;
        if ((unsigned)zi < 9u && (unsigned)yi < 9u && (unsigned)xi < 9u)
            v = *(const half8*)&gridTc[(b * 729 + zi * 81 + yi * 9 + xi) * 64 + ic * 8];
        *(half8*)&slab[pos * 72 + ic * 8] = v;
    }
    __syncthreads();

    int w = tid >> 6;              // wave id = M-tile
    int l = tid & 63;
    int m16 = l & 15, kb = l >> 4;
    int qbase = w * 16;
    int qa = qbase + m16; if (qa > 80) qa = 80;   // clamp pad rows (not stored)
    int ya = qa / 9, xa = qa % 9;
    int laneA = (ya * 11 + xa) * 72 + kb * 8;
    int o0 = nh * 32 + m16;        // conv-frame output channel (acc0); acc1 = +16
    f32x4 acc0 = {0.f, 0.f, 0.f, 0.f};
    f32x4 acc1 = {0.f, 0.f, 0.f, 0.f};

    const half_t* wbase = Wt + (o0 * 64 + kb * 8);

    #pragma unroll
    for (int kd = 0; kd < 3; ++kd)
      #pragma unroll
      for (int kh = 0; kh < 3; ++kh)
        #pragma unroll
        for (int kw = 0; kw < 3; ++kw) {
            int tap = kd * 9 + kh * 3 + kw;
            int sb = laneA + (kd * 121 + kh * 11 + kw) * 72;
            const half_t* wt = wbase + tap * 4096;
            #pragma unroll
            for (int is = 0; is < 2; ++is) {
                half8 a  = *(const half8*)&slab[sb + is * 32];
                half8 b0 = *(const half8*)&wt[is * 32];
                half8 b1 = *(const half8*)&wt[1024 + is * 32];
                acc0 = __builtin_amdgcn_mfma_f32_16x16x32_f16(a, b0, acc0, 0, 0, 0);
                acc1 = __builtin_amdgcn_mfma_f32_16x16x32_f16(a, b1, acc1, 0, 0, 0);
            }
        }

    // D: col = lane&15 -> conv channel o0 (+16), row = kb*4+r -> spatial q.
    // Raw remap: v = (o'&31)*729 + z*81 + q, c = 2b'+nh; bias is conv-frame.
    float c0 = cb1[o0], c1 = cb1[o0 + 16];
    int cG = 2 * b + nh;
    int vb0 = m16 * 729 + z * 81;          // (o0 & 31) = m16
    int vb1 = (m16 + 16) * 729 + z * 81;   // ((o0+16) & 31) = m16+16
    #pragma unroll
    for (int r = 0; r < 4; ++r) {
        int q = qbase + kb * 4 + r;
        if (q < 81) {
            G[(vb0 + q) * 64 + cG] = __float2bfloat16(acc0[r] + c0);
            G[(vb1 + q) * 64 + cG] = __float2bfloat16(acc1[r] + c1);
        }
    }
}

// G[v][c] += sum_k conv0oT[v][k] * L1[k][c]  (lin1 term of G, raw frame).
// B operand = Wt tap 27 = L1^T[c][k]. One wave: 16 v-rows x 64 c.
__global__ __launch_bounds__(256) void k_G2(const half_t* __restrict__ conv0oT,
                                            const half_t* __restrict__ Wt,
                                            bf16* __restrict__ G) {
    int wid = (blockIdx.x * 256 + threadIdx.x) >> 6;
    int v0 = wid * 16;
    if (v0 >= BVOXN) return;
    int l = threadIdx.x & 63;
    int m16 = l & 15, kb = l >> 4;
    const half_t* wt27 = Wt + 27 * 4096;
    f32x4 acc[4];
    #pragma unroll
    for (int ct = 0; ct < 4; ++ct) acc[ct] = {0.f, 0.f, 0.f, 0.f};
    const half_t* ap = conv0oT + (v0 + m16) * 64 + kb * 8;
    #pragma unroll
    for (int is = 0; is < 2; ++is) {
        half8 a = *(const half8*)&ap[is * 32];
        #pragma unroll
        for (int ct = 0; ct < 4; ++ct) {
            half8 bf = *(const half8*)&wt27[(ct * 16 + m16) * 64 + kb * 8 + is * 32];
            acc[ct] = __builtin_amdgcn_mfma_f32_16x16x32_f16(a, bf, acc[ct], 0, 0, 0);
        }
    }
    #pragma unroll
    for (int ct = 0; ct < 4; ++ct)
        #pragma unroll
        for (int r = 0; r < 4; ++r) {
            int v = v0 + kb * 4 + r;
            int c = ct * 16 + m16;
            int idx = v * 64 + c;
            G[idx] = __float2bfloat16(b2f(G[idx]) + acc[ct][r]);
        }
}

// out[i][c] = x[i]@Wc[:,c] + bvec[c] + G[cnc[i]][c]
__global__ __launch_bounds__(256) void k_out(const void* x, const int* cnc,
                                             const float* Wc, const float* bvec,
                                             const bf16* G, const int* flag,
                                             void* out, int N) {
    int t = blockIdx.x * 256 + threadIdx.x;
    int i = t >> 6;
    int c = t & 63;
    if (i >= N) return;
    int isf = *flag;
    int v = cnc[i];
    float x0 = ldf(x, 3 * i + 0, isf);
    float x1 = ldf(x, 3 * i + 1, isf);
    float x2 = ldf(x, 3 * i + 2, isf);
    float r = bvec[c] + x0 * Wc[c] + x1 * Wc[64 + c] + x2 * Wc[128 + c] +
              b2f(G[v * 64 + c]);
    size_t oi = (size_t)i * 64 + c;
    if (isf) ((float*)out)[oi] = r;
    else ((bf16*)out)[oi] = __float2bfloat16(r);
}

// ---------------------------------------------------------------------------
extern "C" void kernel_launch(void* const* d_in, const int* in_sizes, int n_in,
                              void* d_out, int out_size, void* d_ws, size_t ws_size,
                              hipStream_t stream) {
    const void* x       = d_in[0];
    const void* lin0_w  = d_in[1];
    const void* lin0_b  = d_in[2];
    const void* conv0_w = d_in[3];
    const void* conv0_b = d_in[4];
    const void* lin1_w  = d_in[5];
    const void* lin1_b  = d_in[6];
    const void* conv1_w = d_in[7];
    const void* conv1_b = d_in[8];
    const void* linf_w  = d_in[9];
    const void* linf_b  = d_in[10];
    const int* consec   = (const int*)d_in[11];
    const int* cnc      = (const int*)d_in[12];
    const int* unc      = (const int*)d_in[13];

    int N = in_sizes[0] / 3;
    int U = in_sizes[13];

    float* ws   = (float*)d_ws;
    int*   flag = (int*)d_ws;
    unsigned long long* sums8 = (unsigned long long*)(ws + OFF_SUMS);
    float*  gridA0  = ws + OFF_GA0;
    half_t* gridTc  = (half_t*)(ws + OFF_GT);
    half_t* conv0oT = (half_t*)(ws + OFF_C0T);
    half_t* Wt      = (half_t*)(ws + OFF_WT);
    float*  Wc      = ws + OFF_WC;
    float*  bvec    = ws + OFF_BVEC;
    bf16*   G       = (bf16*)(ws + OFF_G);

    // zero sums8 + gridA0 + gridTc (contiguous range)
    hipMemsetAsync((char*)d_ws + (size_t)OFF_SUMS * 4, 0,
                   (size_t)(OFF_C0T - OFF_SUMS) * 4, stream);

    k_probe<<<1, 256, 0, stream>>>(lin1_w, flag);
    k_convert<<<(120576 + 255) / 256, 256, 0, stream>>>(
        lin0_w, lin0_b, conv0_w, conv0_b, lin1_w, lin1_b, conv1_w, conv1_b,
        linf_w, linf_b, flag, ws);
    k_wprep<<<(28 * 4096 + 255) / 256, 256, 0, stream>>>(conv1_w, lin1_w, flag, Wt);
    k_prep<<<1, 64, 0, stream>>>(ws, Wc, bvec);
    k_accum<<<(N + 255) / 256, 256, 0, stream>>>(x, consec, flag, sums8, N);
    k_scatter0<<<(U + 255) / 256, 256, 0, stream>>>(sums8, unc, gridA0, U);
    k_conv0s<<<288, 256, 0, stream>>>(gridA0, ws + OFF_W0, ws + OFF_CB0, conv0oT);
    k_scatter1<<<U, 64, 0, stream>>>(sums8, unc, conv0oT, ws + OFF_L0W, ws + OFF_B0,
                                     gridTc);
    k_conv1m<<<576, 384, 0, stream>>>(gridTc, Wt, ws + OFF_CB1, G);
    k_G2<<<(BVOXN / 16 * 64 + 255) / 256, 256, 0, stream>>>(conv0oT, Wt, G);
    long long tot = (long long)N * 64;
    k_out<<<(int)((tot + 255) / 256), 256, 0, stream>>>(x, cnc, Wc, bvec, G, flag,
                                                        d_out, N);
}

// Round 3
// 564.993 us; speedup vs baseline: 1.3653x; 1.1366x over previous
//
#include <hip/hip_runtime.h>
#include <hip/hip_bf16.h>
#include <stdint.h>

typedef __hip_bfloat16 bf16;
typedef _Float16 half_t;
typedef _Float16 half8 __attribute__((ext_vector_type(8)));
typedef float f32x4 __attribute__((ext_vector_type(4)));
typedef unsigned short us4 __attribute__((ext_vector_type(4)));

#define BVOXN 23328   // B * 729, B = 32 (fixed by setup_inputs)

__device__ __forceinline__ float b2f(bf16 v) { return __bfloat162float(v); }

// ---- workspace layout (float offsets) -------------------------------------
#define OFF_L0W   64        // 192    lin0_w f32
#define OFF_B0    256       // 64     lin0_b
#define OFF_W0    320       // 5184   conv0_w transposed [i][tap][o]
#define OFF_CB0   5504      // 64     conv0_b
#define OFF_L1W   5568      // 4096   lin1_w
#define OFF_B1    9664      // 64     lin1_b
#define OFF_W1T   9728      // 110592 conv1_w f32 (legacy k_convert output, unused)
#define OFF_CB1   120320    // 64     conv1_b
#define OFF_LFW   120384    // 192    linf_w
#define OFF_BF    120576    // 64     linf_b
#define OFF_SUMS  120640    // 93312  u64[46656]: packed per-cluster sums (zeroed)
#define OFF_GA0   213952    // 69984  conv0 input grid f32 (zeroed)
#define OFF_GT    283936    // 746496 slots = half[1492992] conv-frame grid1 (zeroed)
#define OFF_C0T   1030432   // 746496 slots = half[1492992] conv0oT[v_raw][k] (raw)
#define OFF_WT    1776928   // 57344  slots = half[114688] Wt[28][o][i]; tap27 = L1^T
#define OFF_WC    1834272   // 192    folded point matrix
#define OFF_BVEC  1834464   // 64     folded bias
#define OFF_G     1834528   // 746496 slots = bf16[1492992] voxel table G[v_raw][c]
// end = 2581024 f32 = 10.3 MB

// fixed-point packing for cluster sums: e = round(v*2^20) + 2^23 (always >0)
#define FP_SCALE 1048576.0f
#define FP_BIAS  8388608

// ---------------------------------------------------------------------------
// Decide whether float inputs are f32 (flag=1) or bf16 (flag=0).
__global__ void k_probe(const void* lin1_w, int* flag) {
    __shared__ int cnt[256];
    int t = threadIdx.x;
    const bf16* p = (const bf16*)lin1_w;
    int c = 0;
    for (int j = t; j < 2048; j += 256) {
        float v = b2f(p[2 * j]);
        if (!(v == v) || fabsf(v) > 64.0f || (v != 0.0f && fabsf(v) < 1e-20f)) c++;
    }
    cnt[t] = c;
    __syncthreads();
    for (int s = 128; s > 0; s >>= 1) {
        if (t < s) cnt[t] += cnt[t + s];
        __syncthreads();
    }
    if (t == 0) *flag = (cnt[0] > 100) ? 1 : 0;
}

__device__ __forceinline__ float ldf(const void* p, int j, int isf) {
    return isf ? ((const float*)p)[j] : b2f(((const bf16*)p)[j]);
}

// Convert all 10 weight arrays into canonical f32 ws copies (convs transposed).
__global__ void k_convert(const void* l0w, const void* l0b, const void* w0,
                          const void* cb0, const void* l1w, const void* l1b,
                          const void* w1, const void* cb1, const void* lfw,
                          const void* lfb, const int* flag, float* ws) {
    int t = blockIdx.x * 256 + threadIdx.x;
    if (t >= 120576) return;
    int isf = *flag;
    const void* src;
    int j;
    float* dst;
    if (t < 192)        { src = l0w; j = t;          dst = ws + OFF_L0W + j; }
    else if (t < 256)   { src = l0b; j = t - 192;    dst = ws + OFF_B0  + j; }
    else if (t < 5440)  {
        j = t - 256;                        // conv0_w [o][i][tap] -> [i][tap][o]
        int o = j / 81, r = j % 81, i = r / 27, tap = r % 27;
        src = w0;
        dst = ws + OFF_W0 + (i * 27 + tap) * 64 + o;
    }
    else if (t < 5504)  { src = cb0; j = t - 5440;   dst = ws + OFF_CB0 + j; }
    else if (t < 9600)  { src = l1w; j = t - 5504;   dst = ws + OFF_L1W + j; }
    else if (t < 9664)  { src = l1b; j = t - 9600;   dst = ws + OFF_B1  + j; }
    else if (t < 120256) {
        j = t - 9664;                       // conv1_w [o][i][tap] -> [i][tap][o]
        int o = j / 1728, r = j % 1728, i = r / 27, tap = r % 27;
        src = w1;
        dst = ws + OFF_W1T + (i * 27 + tap) * 64 + o;
    }
    else if (t < 120320) { src = cb1; j = t - 120256; dst = ws + OFF_CB1 + j; }
    else if (t < 120512) { src = lfw; j = t - 120320; dst = ws + OFF_LFW + j; }
    else                 { src = lfb; j = t - 120512; dst = ws + OFF_BF  + j; }
    *dst = ldf(src, j, isf);
}

// MFMA weights: Wt[tap][o][i] f16. taps 0..26 = conv1_w; tap 27 = lin1_w^T
// (used by k_G2 as the B operand of the lin1 term of G).
__global__ void k_wprep(const void* w1, const void* l1w, const int* flag,
                        half_t* Wt) {
    int t = blockIdx.x * 256 + threadIdx.x;
    if (t >= 28 * 4096) return;
    int isf = *flag;
    int tap = t >> 12;
    int r = t & 4095;
    int o = r >> 6, i = r & 63;
    float v;
    if (tap < 27) v = ldf(w1, (o * 64 + i) * 27 + tap, isf);   // [o][i][tap]
    else          v = ldf(l1w, i * 64 + o, isf);               // l1w[k][c] -> [c][k]
    Wt[t] = (half_t)v;
}

// Fold: Wc = lin0_w@lin1_w + linf_w [3,64]; bvec = lin0_b@lin1_w + lin1_b + linf_b
__global__ void k_prep(const float* ws, float* Wc, float* bvec) {
    const float* l0w = ws + OFF_L0W;
    const float* l0b = ws + OFF_B0;
    const float* l1w = ws + OFF_L1W;
    const float* l1b = ws + OFF_B1;
    const float* lfw = ws + OFF_LFW;
    const float* lfb = ws + OFF_BF;
    int c = threadIdx.x;
    float bv = l1b[c] + lfb[c];
    for (int k = 0; k < 64; ++k) bv += l0b[k] * l1w[k * 64 + c];
    bvec[c] = bv;
    for (int r = 0; r < 3; ++r) {
        float wv = lfw[r * 64 + c];
        for (int k = 0; k < 64; ++k) wv += l0w[r * 64 + k] * l1w[k * 64 + c];
        Wc[r * 64 + c] = wv;
    }
}

// Per-cluster sums of x (3 ch) + counts: 2 packed u64 atomics per point.
__global__ void k_accum(const void* x, const int* consec, const int* flag,
                        unsigned long long* sums8, int N) {
    int i = blockIdx.x * 256 + threadIdx.x;
    if (i >= N) return;
    int isf = *flag;
    int u = consec[i];
    float v0 = ldf(x, 3 * i + 0, isf);
    float v1 = ldf(x, 3 * i + 1, isf);
    float v2 = ldf(x, 3 * i + 2, isf);
    unsigned e0 = (unsigned)(__float2int_rn(v0 * FP_SCALE) + FP_BIAS);
    unsigned e1 = (unsigned)(__float2int_rn(v1 * FP_SCALE) + FP_BIAS);
    unsigned e2 = (unsigned)(__float2int_rn(v2 * FP_SCALE) + FP_BIAS);
    atomicAdd(&sums8[2 * u + 0], ((unsigned long long)e0 << 32) | e1);
    atomicAdd(&sums8[2 * u + 1], (1ull << 32) | e2);
}

__device__ __forceinline__ void decode_mean(const unsigned long long* sums8, int u,
                                            float& m0, float& m1, float& m2) {
    unsigned long long S1 = sums8[2 * u + 0];
    unsigned long long S2 = sums8[2 * u + 1];
    double n = (double)(unsigned)(S2 >> 32);
    double k = 1.0 / (1048576.0 * n);
    double nb = n * 8388608.0;
    m0 = (float)(((double)(unsigned)(S1 >> 32) - nb) * k);
    m1 = (float)(((double)(unsigned)(S1 & 0xffffffffu) - nb) * k);
    m2 = (float)(((double)(unsigned)(S2 & 0xffffffffu) - nb) * k);
}

// Scatter means into conv0 input grid (flat [3, BVOXN] raw-viewed as (B,3,9,9,9))
__global__ void k_scatter0(const unsigned long long* sums8, const int* unc,
                           float* gridA0, int U) {
    int u = blockIdx.x * 256 + threadIdx.x;
    if (u >= U) return;
    int v = unc[u];
    float m0, m1, m2;
    decode_mean(sums8, u, m0, m1, m2);
    gridA0[0 * BVOXN + v] = m0;
    gridA0[1 * BVOXN + v] = m1;
    gridA0[2 * BVOXN + v] = m2;
}

// conv0: conv-frame (B,3,9,9,9)->(B,64,9,9,9), 3x3x3 pad 1, + bias.
// Output stored in RAW voxel-major layout conv0oT[v_raw][k_raw]:
// conv-frame (b,o,pos) lives at raw flat (b*64+o)*729+pos, i.e.
// k_raw = 2b + (o>>5), v_raw = (o&31)*729 + pos  (reference raw-view semantics).
__global__ __launch_bounds__(256) void k_conv0s(const float* gridA0, const float* w0t,
                                                const float* cb0, half_t* conv0oT) {
    __shared__ float slab[3 * 363];
    int b = blockIdx.x / 9, d = blockIdx.x % 9;
    int t = threadIdx.x;
    for (int s = t; s < 3 * 363; s += 256) {
        int i = s / 363, rr = s % 363;
        int zz = rr / 121, p = rr % 121;
        int ph = p / 11, pw = p % 11;
        int z = d + zz - 1, hh = ph - 1, ww = pw - 1;
        float v = 0.0f;
        if ((unsigned)z < 9u && (unsigned)hh < 9u && (unsigned)ww < 9u)
            v = gridA0[b * 2187 + i * 729 + z * 81 + hh * 9 + ww];
        slab[s] = v;
    }
    __syncthreads();

    int og = t >> 5, l = t & 31;
    int hw[3], hj[3], wj[3];
    bool valid[3];
    #pragma unroll
    for (int j = 0; j < 3; ++j) {
        int q = l + 32 * j;
        valid[j] = q < 81;
        int qc = q < 81 ? q : 80;
        hw[j] = q; hj[j] = qc / 9; wj[j] = qc % 9;
    }
    float acc[8][3];
    #pragma unroll
    for (int oj = 0; oj < 8; ++oj) {
        float bv = cb0[og * 8 + oj];
        acc[oj][0] = bv; acc[oj][1] = bv; acc[oj][2] = bv;
    }

    for (int i = 0; i < 3; ++i) {
        const float* sb = slab + i * 363;
        const float* wb = w0t + (i * 27) * 64 + og * 8;
        for (int kd = 0; kd < 3; ++kd)
            for (int kh = 0; kh < 3; ++kh) {
                int ib0 = kd * 121 + (hj[0] + kh) * 11 + wj[0];
                int ib1 = kd * 121 + (hj[1] + kh) * 11 + wj[1];
                int ib2 = kd * 121 + (hj[2] + kh) * 11 + wj[2];
                #pragma unroll
                for (int kw = 0; kw < 3; ++kw) {
                    int tap = kd * 9 + kh * 3 + kw;
                    const float4* w4 = reinterpret_cast<const float4*>(wb + tap * 64);
                    float4 wA = w4[0];
                    float4 wB = w4[1];
                    float in0 = sb[ib0 + kw];
                    float in1 = sb[ib1 + kw];
                    float in2 = sb[ib2 + kw];
                    acc[0][0] += wA.x * in0; acc[0][1] += wA.x * in1; acc[0][2] += wA.x * in2;
                    acc[1][0] += wA.y * in0; acc[1][1] += wA.y * in1; acc[1][2] += wA.y * in2;
                    acc[2][0] += wA.z * in0; acc[2][1] += wA.z * in1; acc[2][2] += wA.z * in2;
                    acc[3][0] += wA.w * in0; acc[3][1] += wA.w * in1; acc[3][2] += wA.w * in2;
                    acc[4][0] += wB.x * in0; acc[4][1] += wB.x * in1; acc[4][2] += wB.x * in2;
                    acc[5][0] += wB.y * in0; acc[5][1] += wB.y * in1; acc[5][2] += wB.y * in2;
                    acc[6][0] += wB.z * in0; acc[6][1] += wB.z * in1; acc[6][2] += wB.z * in2;
                    acc[7][0] += wB.w * in0; acc[7][1] += wB.w * in1; acc[7][2] += wB.w * in2;
                }
            }
    }

    #pragma unroll
    for (int oj = 0; oj < 8; ++oj) {
        int o = og * 8 + oj;
        int kraw = 2 * b + (o >> 5);
        int bvr = o & 31;
        #pragma unroll
        for (int j = 0; j < 3; ++j)
            if (valid[j])
                conv0oT[(bvr * 729 + d * 81 + hw[j]) * 64 + kraw] =
                    (half_t)acc[oj][j];
    }
}

// conv1 input: raw grid1[c][v] = mean@l0w + l0b + conv0o_raw[c][v] at covered v.
// Written into the CONV-FRAME voxel-major buffer gridTc[(b'*729+pos)*64 + ch']
// with b' = c>>1, ch' = (c&1)*32 + (v/729)  (raw-view reshape semantics).
__global__ void k_scatter1(const unsigned long long* sums8, const int* unc,
                           const half_t* conv0oT, const float* l0w, const float* l0b,
                           half_t* gridTc) {
    int u = blockIdx.x;
    int c = threadIdx.x;
    int v = unc[u];
    int bvr = v / 729, pos = v % 729;
    float m0, m1, m2;
    decode_mean(sums8, u, m0, m1, m2);
    float val = l0b[c] + m0 * l0w[c] + m1 * l0w[64 + c] + m2 * l0w[128 + c] +
                (float)conv0oT[v * 64 + c];
    gridTc[((c >> 1) * 729 + pos) * 64 + ((c & 1) * 32 + bvr)] = (half_t)val;
}

// conv1 via MFMA in the conv frame. Per block: one (b', z, N-half).
// M = 81 spatial (pad 96) over 6 waves, K = 27 taps x 64 ch, N = 32 outputs.
// Epilogue maps conv-frame (b', o', pos) to raw G[(o'&31)*729+pos][2b'+nh].
// LDS slab row stride 72 halfs (144 B): 4 banks mod 32 -> 2-way alias only (free).
__global__ __launch_bounds__(384) void k_conv1m(const half_t* __restrict__ gridTc,
                                                const half_t* __restrict__ Wt,
                                                const float* __restrict__ cb1,
                                                bf16* __restrict__ G) {
    __shared__ __align__(16) half_t slab[363 * 72];
    int bid = blockIdx.x;
    int nh = bid & 1;
    int t2 = bid >> 1;
    int b = t2 / 9, z = t2 % 9;
    int tid = threadIdx.x;

    // stage 3x11x11 halo window (conv-frame), channel-contiguous, zero-padded
    for (int s = tid; s < 2904; s += 384) {
        int pos = s >> 3, ic = s & 7;
        int zz = pos / 121, rr = pos % 121;
        int ph = rr / 11, pw = rr % 11;
        int zi = z + zz - 1, yi = ph - 1, xi = pw - 1;
        half8 v;
        #pragma unroll
        for (int j = 0; j < 8; ++j) v[j] = (half_t)0.f;
        if ((unsigned)zi < 9u && (unsigned)yi < 9u && (unsigned)xi < 9u)
            v = *(const half8*)&gridTc[(b * 729 + zi * 81 + yi * 9 + xi) * 64 + ic * 8];
        *(half8*)&slab[pos * 72 + ic * 8] = v;
    }
    __syncthreads();

    int w = tid >> 6;              // wave id = M-tile
    int l = tid & 63;
    int m16 = l & 15, kb = l >> 4;
    int qbase = w * 16;
    int qa = qbase + m16; if (qa > 80) qa = 80;   // clamp pad rows (not stored)
    int ya = qa / 9, xa = qa % 9;
    int laneA = (ya * 11 + xa) * 72 + kb * 8;
    int o0 = nh * 32 + m16;        // conv-frame output channel (acc0); acc1 = +16
    f32x4 acc0 = {0.f, 0.f, 0.f, 0.f};
    f32x4 acc1 = {0.f, 0.f, 0.f, 0.f};

    const half_t* wbase = Wt + (o0 * 64 + kb * 8);

    #pragma unroll
    for (int kd = 0; kd < 3; ++kd)
      #pragma unroll
      for (int kh = 0; kh < 3; ++kh)
        #pragma unroll
        for (int kw = 0; kw < 3; ++kw) {
            int tap = kd * 9 + kh * 3 + kw;
            int sb = laneA + (kd * 121 + kh * 11 + kw) * 72;
            const half_t* wt = wbase + tap * 4096;
            #pragma unroll
            for (int is = 0; is < 2; ++is) {
                half8 a  = *(const half8*)&slab[sb + is * 32];
                half8 b0 = *(const half8*)&wt[is * 32];
                half8 b1 = *(const half8*)&wt[1024 + is * 32];
                acc0 = __builtin_amdgcn_mfma_f32_16x16x32_f16(a, b0, acc0, 0, 0, 0);
                acc1 = __builtin_amdgcn_mfma_f32_16x16x32_f16(a, b1, acc1, 0, 0, 0);
            }
        }

    // D: col = lane&15 -> conv channel o0 (+16), row = kb*4+r -> spatial q.
    // Raw remap: v = (o'&31)*729 + z*81 + q, c = 2b'+nh; bias is conv-frame.
    float c0 = cb1[o0], c1 = cb1[o0 + 16];
    int cG = 2 * b + nh;
    int vb0 = m16 * 729 + z * 81;          // (o0 & 31) = m16
    int vb1 = (m16 + 16) * 729 + z * 81;   // ((o0+16) & 31) = m16+16
    #pragma unroll
    for (int r = 0; r < 4; ++r) {
        int q = qbase + kb * 4 + r;
        if (q < 81) {
            G[(vb0 + q) * 64 + cG] = __float2bfloat16(acc0[r] + c0);
            G[(vb1 + q) * 64 + cG] = __float2bfloat16(acc1[r] + c1);
        }
    }
}

// G[v][c] += sum_k conv0oT[v][k] * L1[k][c]  (lin1 term of G, raw frame).
// B operand = Wt tap 27 = L1^T[c][k]. One wave: 16 v-rows x 64 c.
__global__ __launch_bounds__(256) void k_G2(const half_t* __restrict__ conv0oT,
                                            const half_t* __restrict__ Wt,
                                            bf16* __restrict__ G) {
    int wid = (blockIdx.x * 256 + threadIdx.x) >> 6;
    int v0 = wid * 16;
    if (v0 >= BVOXN) return;
    int l = threadIdx.x & 63;
    int m16 = l & 15, kb = l >> 4;
    const half_t* wt27 = Wt + 27 * 4096;
    f32x4 acc[4];
    #pragma unroll
    for (int ct = 0; ct < 4; ++ct) acc[ct] = {0.f, 0.f, 0.f, 0.f};
    const half_t* ap = conv0oT + (v0 + m16) * 64 + kb * 8;
    #pragma unroll
    for (int is = 0; is < 2; ++is) {
        half8 a = *(const half8*)&ap[is * 32];
        #pragma unroll
        for (int ct = 0; ct < 4; ++ct) {
            half8 bf = *(const half8*)&wt27[(ct * 16 + m16) * 64 + kb * 8 + is * 32];
            acc[ct] = __builtin_amdgcn_mfma_f32_16x16x32_f16(a, bf, acc[ct], 0, 0, 0);
        }
    }
    #pragma unroll
    for (int ct = 0; ct < 4; ++ct)
        #pragma unroll
        for (int r = 0; r < 4; ++r) {
            int v = v0 + kb * 4 + r;
            int c = ct * 16 + m16;
            int idx = v * 64 + c;
            G[idx] = __float2bfloat16(b2f(G[idx]) + acc[ct][r]);
        }
}

__device__ __forceinline__ unsigned short f2bf_raw(float f) {
    bf16 h = __float2bfloat16(f);
    unsigned short u;
    __builtin_memcpy(&u, &h, 2);
    return u;
}

// out[i][c4..c4+3] = x[i]@Wc + bvec + G[cnc[i]]  — 4 channels per thread:
// ushort4 G load (8B), float4 Wc/bvec loads, float4 (or ushort4) store.
__global__ __launch_bounds__(256) void k_out(const void* x, const int* cnc,
                                             const float* Wc, const float* bvec,
                                             const bf16* G, const int* flag,
                                             void* out, int N) {
    int t = blockIdx.x * 256 + threadIdx.x;
    int i = t >> 4;
    if (i >= N) return;
    int c4 = (t & 15) * 4;
    int isf = *flag;
    int v = cnc[i];
    float x0 = ldf(x, 3 * i + 0, isf);
    float x1 = ldf(x, 3 * i + 1, isf);
    float x2 = ldf(x, 3 * i + 2, isf);
    us4 g = *(const us4*)&G[v * 64 + c4];
    f32x4 w0 = *(const f32x4*)&Wc[c4];
    f32x4 w1 = *(const f32x4*)&Wc[64 + c4];
    f32x4 w2 = *(const f32x4*)&Wc[128 + c4];
    f32x4 bv = *(const f32x4*)&bvec[c4];
    f32x4 r;
    #pragma unroll
    for (int j = 0; j < 4; ++j) {
        float gf = __uint_as_float((unsigned)g[j] << 16);
        r[j] = bv[j] + x0 * w0[j] + x1 * w1[j] + x2 * w2[j] + gf;
    }
    size_t oi = (size_t)i * 64 + c4;
    if (isf) {
        *(f32x4*)((float*)out + oi) = r;
    } else {
        us4 h;
        #pragma unroll
        for (int j = 0; j < 4; ++j) h[j] = f2bf_raw(r[j]);
        *(us4*)((bf16*)out + oi) = h;
    }
}

// ---------------------------------------------------------------------------
extern "C" void kernel_launch(void* const* d_in, const int* in_sizes, int n_in,
                              void* d_out, int out_size, void* d_ws, size_t ws_size,
                              hipStream_t stream) {
    const void* x       = d_in[0];
    const void* lin0_w  = d_in[1];
    const void* lin0_b  = d_in[2];
    const void* conv0_w = d_in[3];
    const void* conv0_b = d_in[4];
    const void* lin1_w  = d_in[5];
    const void* lin1_b  = d_in[6];
    const void* conv1_w = d_in[7];
    const void* conv1_b = d_in[8];
    const void* linf_w  = d_in[9];
    const void* linf_b  = d_in[10];
    const int* consec   = (const int*)d_in[11];
    const int* cnc      = (const int*)d_in[12];
    const int* unc      = (const int*)d_in[13];

    int N = in_sizes[0] / 3;
    int U = in_sizes[13];

    float* ws   = (float*)d_ws;
    int*   flag = (int*)d_ws;
    unsigned long long* sums8 = (unsigned long long*)(ws + OFF_SUMS);
    float*  gridA0  = ws + OFF_GA0;
    half_t* gridTc  = (half_t*)(ws + OFF_GT);
    half_t* conv0oT = (half_t*)(ws + OFF_C0T);
    half_t* Wt      = (half_t*)(ws + OFF_WT);
    float*  Wc      = ws + OFF_WC;
    float*  bvec    = ws + OFF_BVEC;
    bf16*   G       = (bf16*)(ws + OFF_G);

    // zero sums8 + gridA0 + gridTc (contiguous range)
    hipMemsetAsync((char*)d_ws + (size_t)OFF_SUMS * 4, 0,
                   (size_t)(OFF_C0T - OFF_SUMS) * 4, stream);

    k_probe<<<1, 256, 0, stream>>>(lin1_w, flag);
    k_convert<<<(120576 + 255) / 256, 256, 0, stream>>>(
        lin0_w, lin0_b, conv0_w, conv0_b, lin1_w, lin1_b, conv1_w, conv1_b,
        linf_w, linf_b, flag, ws);
    k_wprep<<<(28 * 4096 + 255) / 256, 256, 0, stream>>>(conv1_w, lin1_w, flag, Wt);
    k_prep<<<1, 64, 0, stream>>>(ws, Wc, bvec);
    k_accum<<<(N + 255) / 256, 256, 0, stream>>>(x, consec, flag, sums8, N);
    k_scatter0<<<(U + 255) / 256, 256, 0, stream>>>(sums8, unc, gridA0, U);
    k_conv0s<<<288, 256, 0, stream>>>(gridA0, ws + OFF_W0, ws + OFF_CB0, conv0oT);
    k_scatter1<<<U, 64, 0, stream>>>(sums8, unc, conv0oT, ws + OFF_L0W, ws + OFF_B0,
                                     gridTc);
    k_conv1m<<<576, 384, 0, stream>>>(gridTc, Wt, ws + OFF_CB1, G);
    k_G2<<<(BVOXN / 16 * 64 + 255) / 256, 256, 0, stream>>>(conv0oT, Wt, G);
    long long tot = (long long)N * 16;
    k_out<<<(int)((tot + 255) / 256), 256, 0, stream>>>(x, cnc, Wc, bvec, G, flag,
                                                        d_out, N);
}

// Round 4
// 552.177 us; speedup vs baseline: 1.3970x; 1.0232x over previous
//
#include <hip/hip_runtime.h>
#include <hip/hip_bf16.h>
#include <stdint.h>

typedef __hip_bfloat16 bf16;
typedef _Float16 half_t;
typedef _Float16 half8 __attribute__((ext_vector_type(8)));
typedef float f32x4 __attribute__((ext_vector_type(4)));
typedef unsigned short us8 __attribute__((ext_vector_type(8)));

#define BVOXN 23328   // B * 729, B = 32 (fixed by setup_inputs)

__device__ __forceinline__ float b2f(bf16 v) { return __bfloat162float(v); }

// ---- workspace layout (float offsets) -------------------------------------
#define OFF_L0W   64        // 192    lin0_w f32
#define OFF_B0    256       // 64     lin0_b
#define OFF_W0    320       // 5184   conv0_w transposed [i][tap][o]
#define OFF_CB0   5504      // 64     conv0_b
#define OFF_L1W   5568      // 4096   (unused, kept for layout stability)
#define OFF_B1    9664      // 64     (unused)
#define OFF_CB1   120320    // 64     conv1_b
#define OFF_LFW   120384    // 192    (unused)
#define OFF_BF    120576    // 64     (unused)
#define OFF_SUMS  120640    // 93312  u64[46656]: packed per-cluster sums (zeroed)
#define OFF_GA0   213952    // 69984  conv0 input grid f32 (zeroed)
#define OFF_GT    283936    // 746496 slots = half[1492992] conv-frame grid1 (zeroed)
#define OFF_C0T   1030432   // 746496 slots = half[1492992] conv0oT[v_raw][k] (raw)
#define OFF_WT    1776928   // 57344  slots = half[114688] Wt[28][o][i]; tap27 = L1^T
#define OFF_WC    1834272   // 192    folded point matrix
#define OFF_BVEC  1834464   // 64     folded bias
#define OFF_G     1834528   // 746496 slots = bf16[1492992] voxel table G[v_raw][c]
// end = 2581024 f32 = 10.3 MB

// fixed-point packing for cluster sums: e = round(v*2^20) + 2^23 (always >0)
#define FP_SCALE 1048576.0f
#define FP_BIAS  8388608

// ---------------------------------------------------------------------------
// Decide whether float inputs are f32 (flag=1) or bf16 (flag=0).
__global__ void k_probe(const void* lin1_w, int* flag) {
    __shared__ int cnt[256];
    int t = threadIdx.x;
    const bf16* p = (const bf16*)lin1_w;
    int c = 0;
    for (int j = t; j < 2048; j += 256) {
        float v = b2f(p[2 * j]);
        if (!(v == v) || fabsf(v) > 64.0f || (v != 0.0f && fabsf(v) < 1e-20f)) c++;
    }
    cnt[t] = c;
    __syncthreads();
    for (int s = 128; s > 0; s >>= 1) {
        if (t < s) cnt[t] += cnt[t + s];
        __syncthreads();
    }
    if (t == 0) *flag = (cnt[0] > 100) ? 1 : 0;
}

__device__ __forceinline__ float ldf(const void* p, int j, int isf) {
    return isf ? ((const float*)p)[j] : b2f(((const bf16*)p)[j]);
}

// Merged setup: weight conversion (f32 ws copies), MFMA weight pack (f16 Wt),
// and the folded point-matrix prep (reads RAW inputs, so no grid dependency).
// t-map: [0,192) l0w | [192,256) l0b | [256,5440) w0-transpose |
// [5440,5504) cb0 | [5504,5568) cb1 | [5568,120256) Wt pack.
// Last block (tid<64) computes Wc/bvec from raw inputs.
#define SETUP_N 120256
__global__ void k_setup(const void* l0w, const void* l0b, const void* w0,
                        const void* cb0, const void* l1w, const void* l1b,
                        const void* w1, const void* cb1, const void* lfw,
                        const void* lfb, const int* flag, float* ws,
                        half_t* Wt, float* Wc, float* bvec) {
    int isf = *flag;
    int t = blockIdx.x * 256 + threadIdx.x;
    if (t < SETUP_N) {
        if (t < 5568) {
            const void* src;
            int j;
            float* dst;
            if (t < 192)       { src = l0w; j = t;         dst = ws + OFF_L0W + j; }
            else if (t < 256)  { src = l0b; j = t - 192;   dst = ws + OFF_B0  + j; }
            else if (t < 5440) {
                j = t - 256;                    // conv0_w [o][i][tap] -> [i][tap][o]
                int o = j / 81, r = j % 81, i = r / 27, tap = r % 27;
                src = w0;
                dst = ws + OFF_W0 + (i * 27 + tap) * 64 + o;
            }
            else if (t < 5504) { src = cb0; j = t - 5440;  dst = ws + OFF_CB0 + j; }
            else               { src = cb1; j = t - 5504;  dst = ws + OFF_CB1 + j; }
            *dst = ldf(src, j, isf);
        } else {
            // Wt[tap][o][i] f16: taps 0..26 = conv1_w [o][i][tap]; tap27 = l1w^T
            int q = t - 5568;
            int tap = q >> 12;
            int r = q & 4095;
            int o = r >> 6, i = r & 63;
            float v;
            if (tap < 27) v = ldf(w1, (o * 64 + i) * 27 + tap, isf);
            else          v = ldf(l1w, i * 64 + o, isf);
            Wt[q] = (half_t)v;
        }
        return;
    }
    // prep block: Wc = lin0_w@lin1_w + linf_w; bvec = lin0_b@lin1_w + lin1_b + linf_b
    if (blockIdx.x == (SETUP_N + 255) / 256 && threadIdx.x < 64) {
        int c = threadIdx.x;
        float bv = ldf(l1b, c, isf) + ldf(lfb, c, isf);
        for (int k = 0; k < 64; ++k)
            bv += ldf(l0b, k, isf) * ldf(l1w, k * 64 + c, isf);
        bvec[c] = bv;
        for (int r = 0; r < 3; ++r) {
            float wv = ldf(lfw, r * 64 + c, isf);
            for (int k = 0; k < 64; ++k)
                wv += ldf(l0w, r * 64 + k, isf) * ldf(l1w, k * 64 + c, isf);
            Wc[r * 64 + c] = wv;
        }
    }
}

// Per-cluster sums of x (3 ch) + counts: 2 packed u64 atomics per point.
__global__ void k_accum(const void* x, const int* consec, const int* flag,
                        unsigned long long* sums8, int N) {
    int i = blockIdx.x * 256 + threadIdx.x;
    if (i >= N) return;
    int isf = *flag;
    int u = consec[i];
    float v0 = ldf(x, 3 * i + 0, isf);
    float v1 = ldf(x, 3 * i + 1, isf);
    float v2 = ldf(x, 3 * i + 2, isf);
    unsigned e0 = (unsigned)(__float2int_rn(v0 * FP_SCALE) + FP_BIAS);
    unsigned e1 = (unsigned)(__float2int_rn(v1 * FP_SCALE) + FP_BIAS);
    unsigned e2 = (unsigned)(__float2int_rn(v2 * FP_SCALE) + FP_BIAS);
    atomicAdd(&sums8[2 * u + 0], ((unsigned long long)e0 << 32) | e1);
    atomicAdd(&sums8[2 * u + 1], (1ull << 32) | e2);
}

__device__ __forceinline__ void decode_mean(const unsigned long long* sums8, int u,
                                            float& m0, float& m1, float& m2) {
    unsigned long long S1 = sums8[2 * u + 0];
    unsigned long long S2 = sums8[2 * u + 1];
    double n = (double)(unsigned)(S2 >> 32);
    double k = 1.0 / (1048576.0 * n);
    double nb = n * 8388608.0;
    m0 = (float)(((double)(unsigned)(S1 >> 32) - nb) * k);
    m1 = (float)(((double)(unsigned)(S1 & 0xffffffffu) - nb) * k);
    m2 = (float)(((double)(unsigned)(S2 & 0xffffffffu) - nb) * k);
}

// Scatter means into conv0 input grid (flat [3, BVOXN] raw-viewed as (B,3,9,9,9))
__global__ void k_scatter0(const unsigned long long* sums8, const int* unc,
                           float* gridA0, int U) {
    int u = blockIdx.x * 256 + threadIdx.x;
    if (u >= U) return;
    int v = unc[u];
    float m0, m1, m2;
    decode_mean(sums8, u, m0, m1, m2);
    gridA0[0 * BVOXN + v] = m0;
    gridA0[1 * BVOXN + v] = m1;
    gridA0[2 * BVOXN + v] = m2;
}

// conv0: conv-frame (B,3,9,9,9)->(B,64,9,9,9), 3x3x3 pad 1, + bias.
// Output stored in RAW voxel-major layout conv0oT[v_raw][k_raw]:
// conv-frame (b,o,pos) lives at raw flat (b*64+o)*729+pos, i.e.
// k_raw = 2b + (o>>5), v_raw = (o&31)*729 + pos  (reference raw-view semantics).
__global__ __launch_bounds__(256) void k_conv0s(const float* gridA0, const float* w0t,
                                                const float* cb0, half_t* conv0oT) {
    __shared__ float slab[3 * 363];
    int b = blockIdx.x / 9, d = blockIdx.x % 9;
    int t = threadIdx.x;
    for (int s = t; s < 3 * 363; s += 256) {
        int i = s / 363, rr = s % 363;
        int zz = rr / 121, p = rr % 121;
        int ph = p / 11, pw = p % 11;
        int z = d + zz - 1, hh = ph - 1, ww = pw - 1;
        float v = 0.0f;
        if ((unsigned)z < 9u && (unsigned)hh < 9u && (unsigned)ww < 9u)
            v = gridA0[b * 2187 + i * 729 + z * 81 + hh * 9 + ww];
        slab[s] = v;
    }
    __syncthreads();

    int og = t >> 5, l = t & 31;
    int hw[3], hj[3], wj[3];
    bool valid[3];
    #pragma unroll
    for (int j = 0; j < 3; ++j) {
        int q = l + 32 * j;
        valid[j] = q < 81;
        int qc = q < 81 ? q : 80;
        hw[j] = q; hj[j] = qc / 9; wj[j] = qc % 9;
    }
    float acc[8][3];
    #pragma unroll
    for (int oj = 0; oj < 8; ++oj) {
        float bv = cb0[og * 8 + oj];
        acc[oj][0] = bv; acc[oj][1] = bv; acc[oj][2] = bv;
    }

    for (int i = 0; i < 3; ++i) {
        const float* sb = slab + i * 363;
        const float* wb = w0t + (i * 27) * 64 + og * 8;
        for (int kd = 0; kd < 3; ++kd)
            for (int kh = 0; kh < 3; ++kh) {
                int ib0 = kd * 121 + (hj[0] + kh) * 11 + wj[0];
                int ib1 = kd * 121 + (hj[1] + kh) * 11 + wj[1];
                int ib2 = kd * 121 + (hj[2] + kh) * 11 + wj[2];
                #pragma unroll
                for (int kw = 0; kw < 3; ++kw) {
                    int tap = kd * 9 + kh * 3 + kw;
                    const float4* w4 = reinterpret_cast<const float4*>(wb + tap * 64);
                    float4 wA = w4[0];
                    float4 wB = w4[1];
                    float in0 = sb[ib0 + kw];
                    float in1 = sb[ib1 + kw];
                    float in2 = sb[ib2 + kw];
                    acc[0][0] += wA.x * in0; acc[0][1] += wA.x * in1; acc[0][2] += wA.x * in2;
                    acc[1][0] += wA.y * in0; acc[1][1] += wA.y * in1; acc[1][2] += wA.y * in2;
                    acc[2][0] += wA.z * in0; acc[2][1] += wA.z * in1; acc[2][2] += wA.z * in2;
                    acc[3][0] += wA.w * in0; acc[3][1] += wA.w * in1; acc[3][2] += wA.w * in2;
                    acc[4][0] += wB.x * in0; acc[4][1] += wB.x * in1; acc[4][2] += wB.x * in2;
                    acc[5][0] += wB.y * in0; acc[5][1] += wB.y * in1; acc[5][2] += wB.y * in2;
                    acc[6][0] += wB.z * in0; acc[6][1] += wB.z * in1; acc[6][2] += wB.z * in2;
                    acc[7][0] += wB.w * in0; acc[7][1] += wB.w * in1; acc[7][2] += wB.w * in2;
                }
            }
    }

    #pragma unroll
    for (int oj = 0; oj < 8; ++oj) {
        int o = og * 8 + oj;
        int kraw = 2 * b + (o >> 5);
        int bvr = o & 31;
        #pragma unroll
        for (int j = 0; j < 3; ++j)
            if (valid[j])
                conv0oT[(bvr * 729 + d * 81 + hw[j]) * 64 + kraw] =
                    (half_t)acc[oj][j];
    }
}

// conv1 input: raw grid1[c][v] = mean@l0w + l0b + conv0o_raw[c][v] at covered v.
// Written into the CONV-FRAME voxel-major buffer gridTc[(b'*729+pos)*64 + ch']
// with b' = c>>1, ch' = (c&1)*32 + (v/729)  (raw-view reshape semantics).
// 4 clusters per 256-thread block for better CU packing.
__global__ __launch_bounds__(256) void k_scatter1(const unsigned long long* sums8,
                                                  const int* unc,
                                                  const half_t* conv0oT,
                                                  const float* l0w, const float* l0b,
                                                  half_t* gridTc, int U) {
    int u = blockIdx.x * 4 + (threadIdx.x >> 6);
    if (u >= U) return;
    int c = threadIdx.x & 63;
    int v = unc[u];
    int bvr = v / 729, pos = v % 729;
    float m0, m1, m2;
    decode_mean(sums8, u, m0, m1, m2);
    float val = l0b[c] + m0 * l0w[c] + m1 * l0w[64 + c] + m2 * l0w[128 + c] +
                (float)conv0oT[v * 64 + c];
    gridTc[((c >> 1) * 729 + pos) * 64 + ((c & 1) * 32 + bvr)] = (half_t)val;
}

// conv1 via MFMA in the conv frame. Per block: one (b', z, N-half).
// M = 81 spatial (pad 96) over 6 waves, K = 27 taps x 64 ch, N = 32 outputs.
// Epilogue maps conv-frame (b', o', pos) to raw G[(o'&31)*729+pos][2b'+nh].
// LDS slab row stride 72 halfs (144 B): 4 banks mod 32 -> 2-way alias only (free).
__global__ __launch_bounds__(384) void k_conv1m(const half_t* __restrict__ gridTc,
                                                const half_t* __restrict__ Wt,
                                                const float* __restrict__ cb1,
                                                bf16* __restrict__ G) {
    __shared__ __align__(16) half_t slab[363 * 72];
    int bid = blockIdx.x;
    int nh = bid & 1;
    int t2 = bid >> 1;
    int b = t2 / 9, z = t2 % 9;
    int tid = threadIdx.x;

    // stage 3x11x11 halo window (conv-frame), channel-contiguous, zero-padded
    for (int s = tid; s < 2904; s += 384) {
        int pos = s >> 3, ic = s & 7;
        int zz = pos / 121, rr = pos % 121;
        int ph = rr / 11, pw = rr % 11;
        int zi = z + zz - 1, yi = ph - 1, xi = pw - 1;
        half8 v;
        #pragma unroll
        for (int j = 0; j < 8; ++j) v[j] = (half_t)0.f;
        if ((unsigned)zi < 9u && (unsigned)yi < 9u && (unsigned)xi < 9u)
            v = *(const half8*)&gridTc[(b * 729 + zi * 81 + yi * 9 + xi) * 64 + ic * 8];
        *(half8*)&slab[pos * 72 + ic * 8] = v;
    }
    __syncthreads();

    int w = tid >> 6;              // wave id = M-tile
    int l = tid & 63;
    int m16 = l & 15, kb = l >> 4;
    int qbase = w * 16;
    int qa = qbase + m16; if (qa > 80) qa = 80;   // clamp pad rows (not stored)
    int ya = qa / 9, xa = qa % 9;
    int laneA = (ya * 11 + xa) * 72 + kb * 8;
    int o0 = nh * 32 + m16;        // conv-frame output channel (acc0); acc1 = +16
    f32x4 acc0 = {0.f, 0.f, 0.f, 0.f};
    f32x4 acc1 = {0.f, 0.f, 0.f, 0.f};

    const half_t* wbase = Wt + (o0 * 64 + kb * 8);

    #pragma unroll
    for (int kd = 0; kd < 3; ++kd)
      #pragma unroll
      for (int kh = 0; kh < 3; ++kh)
        #pragma unroll
        for (int kw = 0; kw < 3; ++kw) {
            int tap = kd * 9 + kh * 3 + kw;
            int sb = laneA + (kd * 121 + kh * 11 + kw) * 72;
            const half_t* wt = wbase + tap * 4096;
            #pragma unroll
            for (int is = 0; is < 2; ++is) {
                half8 a  = *(const half8*)&slab[sb + is * 32];
                half8 b0 = *(const half8*)&wt[is * 32];
                half8 b1 = *(const half8*)&wt[1024 + is * 32];
                acc0 = __builtin_amdgcn_mfma_f32_16x16x32_f16(a, b0, acc0, 0, 0, 0);
                acc1 = __builtin_amdgcn_mfma_f32_16x16x32_f16(a, b1, acc1, 0, 0, 0);
            }
        }

    // D: col = lane&15 -> conv channel o0 (+16), row = kb*4+r -> spatial q.
    // Raw remap: v = (o'&31)*729 + z*81 + q, c = 2b'+nh; bias is conv-frame.
    float c0 = cb1[o0], c1 = cb1[o0 + 16];
    int cG = 2 * b + nh;
    int vb0 = m16 * 729 + z * 81;          // (o0 & 31) = m16
    int vb1 = (m16 + 16) * 729 + z * 81;   // ((o0+16) & 31) = m16+16
    #pragma unroll
    for (int r = 0; r < 4; ++r) {
        int q = qbase + kb * 4 + r;
        if (q < 81) {
            G[(vb0 + q) * 64 + cG] = __float2bfloat16(acc0[r] + c0);
            G[(vb1 + q) * 64 + cG] = __float2bfloat16(acc1[r] + c1);
        }
    }
}

// G[v][c] += sum_k conv0oT[v][k] * L1[k][c]  (lin1 term of G, raw frame).
// B operand = Wt tap 27 = L1^T[c][k]. One wave: 16 v-rows x 64 c.
__global__ __launch_bounds__(256) void k_G2(const half_t* __restrict__ conv0oT,
                                            const half_t* __restrict__ Wt,
                                            bf16* __restrict__ G) {
    int wid = (blockIdx.x * 256 + threadIdx.x) >> 6;
    int v0 = wid * 16;
    if (v0 >= BVOXN) return;
    int l = threadIdx.x & 63;
    int m16 = l & 15, kb = l >> 4;
    const half_t* wt27 = Wt + 27 * 4096;
    f32x4 acc[4];
    #pragma unroll
    for (int ct = 0; ct < 4; ++ct) acc[ct] = {0.f, 0.f, 0.f, 0.f};
    const half_t* ap = conv0oT + (v0 + m16) * 64 + kb * 8;
    #pragma unroll
    for (int is = 0; is < 2; ++is) {
        half8 a = *(const half8*)&ap[is * 32];
        #pragma unroll
        for (int ct = 0; ct < 4; ++ct) {
            half8 bf = *(const half8*)&wt27[(ct * 16 + m16) * 64 + kb * 8 + is * 32];
            acc[ct] = __builtin_amdgcn_mfma_f32_16x16x32_f16(a, bf, acc[ct], 0, 0, 0);
        }
    }
    #pragma unroll
    for (int ct = 0; ct < 4; ++ct)
        #pragma unroll
        for (int r = 0; r < 4; ++r) {
            int v = v0 + kb * 4 + r;
            int c = ct * 16 + m16;
            int idx = v * 64 + c;
            G[idx] = __float2bfloat16(b2f(G[idx]) + acc[ct][r]);
        }
}

__device__ __forceinline__ unsigned short f2bf_raw(float f) {
    bf16 h = __float2bfloat16(f);
    unsigned short u;
    __builtin_memcpy(&u, &h, 2);
    return u;
}

// out[i][c8..c8+7] = x[i]@Wc + bvec + G[cnc[i]]  — 8 channels per thread:
// ushort8 G load (16B, 8 lanes cover a 128B G row), 2x float4 stores.
__global__ __launch_bounds__(256) void k_out(const void* x, const int* cnc,
                                             const float* Wc, const float* bvec,
                                             const bf16* G, const int* flag,
                                             void* out, int N) {
    int t = blockIdx.x * 256 + threadIdx.x;
    int i = t >> 3;
    if (i >= N) return;
    int c8 = (t & 7) * 8;
    int isf = *flag;
    int v = cnc[i];
    float x0 = ldf(x, 3 * i + 0, isf);
    float x1 = ldf(x, 3 * i + 1, isf);
    float x2 = ldf(x, 3 * i + 2, isf);
    us8 g = *(const us8*)&G[v * 64 + c8];
    f32x4 w0a = *(const f32x4*)&Wc[c8];
    f32x4 w0b = *(const f32x4*)&Wc[c8 + 4];
    f32x4 w1a = *(const f32x4*)&Wc[64 + c8];
    f32x4 w1b = *(const f32x4*)&Wc[64 + c8 + 4];
    f32x4 w2a = *(const f32x4*)&Wc[128 + c8];
    f32x4 w2b = *(const f32x4*)&Wc[128 + c8 + 4];
    f32x4 bva = *(const f32x4*)&bvec[c8];
    f32x4 bvb = *(const f32x4*)&bvec[c8 + 4];
    f32x4 ra, rb;
    #pragma unroll
    for (int j = 0; j < 4; ++j) {
        float gfa = __uint_as_float((unsigned)g[j] << 16);
        float gfb = __uint_as_float((unsigned)g[j + 4] << 16);
        ra[j] = bva[j] + x0 * w0a[j] + x1 * w1a[j] + x2 * w2a[j] + gfa;
        rb[j] = bvb[j] + x0 * w0b[j] + x1 * w1b[j] + x2 * w2b[j] + gfb;
    }
    size_t oi = (size_t)i * 64 + c8;
    if (isf) {
        *(f32x4*)((float*)out + oi) = ra;
        *(f32x4*)((float*)out + oi + 4) = rb;
    } else {
        us8 h;
        #pragma unroll
        for (int j = 0; j < 4; ++j) {
            h[j] = f2bf_raw(ra[j]);
            h[j + 4] = f2bf_raw(rb[j]);
        }
        *(us8*)((bf16*)out + oi) = h;
    }
}

// ---------------------------------------------------------------------------
extern "C" void kernel_launch(void* const* d_in, const int* in_sizes, int n_in,
                              void* d_out, int out_size, void* d_ws, size_t ws_size,
                              hipStream_t stream) {
    const void* x       = d_in[0];
    const void* lin0_w  = d_in[1];
    const void* lin0_b  = d_in[2];
    const void* conv0_w = d_in[3];
    const void* conv0_b = d_in[4];
    const void* lin1_w  = d_in[5];
    const void* lin1_b  = d_in[6];
    const void* conv1_w = d_in[7];
    const void* conv1_b = d_in[8];
    const void* linf_w  = d_in[9];
    const void* linf_b  = d_in[10];
    const int* consec   = (const int*)d_in[11];
    const int* cnc      = (const int*)d_in[12];
    const int* unc      = (const int*)d_in[13];

    int N = in_sizes[0] / 3;
    int U = in_sizes[13];

    float* ws   = (float*)d_ws;
    int*   flag = (int*)d_ws;
    unsigned long long* sums8 = (unsigned long long*)(ws + OFF_SUMS);
    float*  gridA0  = ws + OFF_GA0;
    half_t* gridTc  = (half_t*)(ws + OFF_GT);
    half_t* conv0oT = (half_t*)(ws + OFF_C0T);
    half_t* Wt      = (half_t*)(ws + OFF_WT);
    float*  Wc      = ws + OFF_WC;
    float*  bvec    = ws + OFF_BVEC;
    bf16*   G       = (bf16*)(ws + OFF_G);

    // zero sums8 + gridA0 + gridTc (contiguous range)
    hipMemsetAsync((char*)d_ws + (size_t)OFF_SUMS * 4, 0,
                   (size_t)(OFF_C0T - OFF_SUMS) * 4, stream);

    k_probe<<<1, 256, 0, stream>>>(lin1_w, flag);
    // setup grid: SETUP_N worker threads + 1 extra block for the prep fold
    k_setup<<<(SETUP_N + 255) / 256 + 1, 256, 0, stream>>>(
        lin0_w, lin0_b, conv0_w, conv0_b, lin1_w, lin1_b, conv1_w, conv1_b,
        linf_w, linf_b, flag, ws, Wt, Wc, bvec);
    k_accum<<<(N + 255) / 256, 256, 0, stream>>>(x, consec, flag, sums8, N);
    k_scatter0<<<(U + 255) / 256, 256, 0, stream>>>(sums8, unc, gridA0, U);
    k_conv0s<<<288, 256, 0, stream>>>(gridA0, ws + OFF_W0, ws + OFF_CB0, conv0oT);
    k_scatter1<<<(U + 3) / 4, 256, 0, stream>>>(sums8, unc, conv0oT, ws + OFF_L0W,
                                                ws + OFF_B0, gridTc, U);
    k_conv1m<<<576, 384, 0, stream>>>(gridTc, Wt, ws + OFF_CB1, G);
    k_G2<<<(BVOXN / 16 * 64 + 255) / 256, 256, 0, stream>>>(conv0oT, Wt, G);
    long long tot = (long long)N * 8;
    k_out<<<(int)((tot + 255) / 256), 256, 0, stream>>>(x, cnc, Wc, bvec, G, flag,
                                                        d_out, N);
}

// Round 5
// 546.402 us; speedup vs baseline: 1.4118x; 1.0106x over previous
//
#include <hip/hip_runtime.h>
#include <hip/hip_bf16.h>
#include <stdint.h>

typedef __hip_bfloat16 bf16;
typedef _Float16 half_t;
typedef _Float16 half8 __attribute__((ext_vector_type(8)));
typedef float f32x4 __attribute__((ext_vector_type(4)));
typedef unsigned short us8 __attribute__((ext_vector_type(8)));

#define BVOXN 23328   // B * 729, B = 32 (fixed by setup_inputs)

__device__ __forceinline__ float b2f(bf16 v) { return __bfloat162float(v); }

// ---- workspace layout (float offsets) -------------------------------------
#define OFF_L0W   64        // 192    lin0_w f32
#define OFF_B0    256       // 64     lin0_b
#define OFF_W0    320       // 5184   conv0_w transposed [i][tap][o]
#define OFF_CB0   5504      // 64     conv0_b
#define OFF_CB1   120320    // 64     conv1_b
#define OFF_SUMS  120640    // 93312  u64[46656]: packed per-cluster sums (zeroed)
#define OFF_GA0   213952    // 69984  conv0 input grid f32 (zeroed)
#define OFF_MEX   283936    // 93312  f32x4[23328] meanex[v]={m0,m1,m2,flag} (zeroed)
#define OFF_GT    377248    // 746496 slots = half[1492992] conv-frame grid1
#define OFF_C0T   1123744   // 746496 slots = half[1492992] conv0oT[v_raw][k] (raw)
#define OFF_WT    1870240   // 57344  slots = half[114688] Wt[28][o][i]; tap27 = L1^T
#define OFF_WC    1927584   // 192    folded point matrix
#define OFF_BVEC  1927776   // 64     folded bias
#define OFF_G     1927840   // 746496 slots = bf16[1492992] voxel table G[v_raw][c]
// end = 2674336 f32 = 10.7 MB

// fixed-point packing for cluster sums: e = round(v*2^20) + 2^23 (always >0)
#define FP_SCALE 1048576.0f
#define FP_BIAS  8388608

// ---------------------------------------------------------------------------
// Decide whether float inputs are f32 (flag=1) or bf16 (flag=0).
__global__ void k_probe(const void* lin1_w, int* flag) {
    __shared__ int cnt[256];
    int t = threadIdx.x;
    const bf16* p = (const bf16*)lin1_w;
    int c = 0;
    for (int j = t; j < 2048; j += 256) {
        float v = b2f(p[2 * j]);
        if (!(v == v) || fabsf(v) > 64.0f || (v != 0.0f && fabsf(v) < 1e-20f)) c++;
    }
    cnt[t] = c;
    __syncthreads();
    for (int s = 128; s > 0; s >>= 1) {
        if (t < s) cnt[t] += cnt[t + s];
        __syncthreads();
    }
    if (t == 0) *flag = (cnt[0] > 100) ? 1 : 0;
}

__device__ __forceinline__ float ldf(const void* p, int j, int isf) {
    return isf ? ((const float*)p)[j] : b2f(((const bf16*)p)[j]);
}

// Merged setup + accum (both depend only on flag).
// Blocks [0, NA): per-point cluster-sum atomics.
// Blocks [NA, NA+470): weight conversion + Wt pack.
// Block NA+470 (tid<64): folded point matrix Wc/bvec from raw inputs.
#define SETUP_N 120256
__global__ void k_sa(const void* x, const int* consec, int N, int NA,
                     const void* l0w, const void* l0b, const void* w0,
                     const void* cb0, const void* l1w, const void* l1b,
                     const void* w1, const void* cb1, const void* lfw,
                     const void* lfb, const int* flag, float* ws,
                     half_t* Wt, float* Wc, float* bvec,
                     unsigned long long* sums8) {
    int isf = *flag;
    int bid = blockIdx.x;
    if (bid < NA) {
        int i = bid * 256 + threadIdx.x;
        if (i >= N) return;
        int u = consec[i];
        float v0 = ldf(x, 3 * i + 0, isf);
        float v1 = ldf(x, 3 * i + 1, isf);
        float v2 = ldf(x, 3 * i + 2, isf);
        unsigned e0 = (unsigned)(__float2int_rn(v0 * FP_SCALE) + FP_BIAS);
        unsigned e1 = (unsigned)(__float2int_rn(v1 * FP_SCALE) + FP_BIAS);
        unsigned e2 = (unsigned)(__float2int_rn(v2 * FP_SCALE) + FP_BIAS);
        atomicAdd(&sums8[2 * u + 0], ((unsigned long long)e0 << 32) | e1);
        atomicAdd(&sums8[2 * u + 1], (1ull << 32) | e2);
        return;
    }
    int t = (bid - NA) * 256 + threadIdx.x;
    if (t < SETUP_N) {
        if (t < 5568) {
            const void* src;
            int j;
            float* dst;
            if (t < 192)       { src = l0w; j = t;         dst = ws + OFF_L0W + j; }
            else if (t < 256)  { src = l0b; j = t - 192;   dst = ws + 256 + (j = t - 192, j); }
            else if (t < 5440) {
                j = t - 256;                    // conv0_w [o][i][tap] -> [i][tap][o]
                int o = j / 81, r = j % 81, i = r / 27, tap = r % 27;
                src = w0;
                dst = ws + OFF_W0 + (i * 27 + tap) * 64 + o;
            }
            else if (t < 5504) { src = cb0; j = t - 5440;  dst = ws + OFF_CB0 + j; }
            else               { src = cb1; j = t - 5504;  dst = ws + OFF_CB1 + j; }
            if (t >= 192 && t < 256) { src = l0b; j = t - 192; dst = ws + OFF_B0 + j; }
            *dst = ldf(src, j, isf);
        } else {
            // Wt[tap][o][i] f16: taps 0..26 = conv1_w [o][i][tap]; tap27 = l1w^T
            int q = t - 5568;
            int tap = q >> 12;
            int r = q & 4095;
            int o = r >> 6, i = r & 63;
            float v;
            if (tap < 27) v = ldf(w1, (o * 64 + i) * 27 + tap, isf);
            else          v = ldf(l1w, i * 64 + o, isf);
            Wt[q] = (half_t)v;
        }
        return;
    }
    // prep block: Wc = lin0_w@lin1_w + linf_w; bvec = lin0_b@lin1_w + lin1_b + linf_b
    if (bid == NA + (SETUP_N + 255) / 256 && threadIdx.x < 64) {
        int c = threadIdx.x;
        float bv = ldf(l1b, c, isf) + ldf(lfb, c, isf);
        for (int k = 0; k < 64; ++k)
            bv += ldf(l0b, k, isf) * ldf(l1w, k * 64 + c, isf);
        bvec[c] = bv;
        for (int r = 0; r < 3; ++r) {
            float wv = ldf(lfw, r * 64 + c, isf);
            for (int k = 0; k < 64; ++k)
                wv += ldf(l0w, r * 64 + k, isf) * ldf(l1w, k * 64 + c, isf);
            Wc[r * 64 + c] = wv;
        }
    }
}

__device__ __forceinline__ void decode_mean(const unsigned long long* sums8, int u,
                                            float& m0, float& m1, float& m2) {
    unsigned long long S1 = sums8[2 * u + 0];
    unsigned long long S2 = sums8[2 * u + 1];
    double n = (double)(unsigned)(S2 >> 32);
    double k = 1.0 / (1048576.0 * n);
    double nb = n * 8388608.0;
    m0 = (float)(((double)(unsigned)(S1 >> 32) - nb) * k);
    m1 = (float)(((double)(unsigned)(S1 & 0xffffffffu) - nb) * k);
    m2 = (float)(((double)(unsigned)(S2 & 0xffffffffu) - nb) * k);
}

// Scatter means into conv0 input grid (flat [3, BVOXN] raw-view) AND the
// voxel-indexed meanex table {m0,m1,m2,flag} used by the grid1 gather.
__global__ void k_scatter0(const unsigned long long* sums8, const int* unc,
                           float* gridA0, f32x4* meanex, int U) {
    int u = blockIdx.x * 256 + threadIdx.x;
    if (u >= U) return;
    int v = unc[u];
    float m0, m1, m2;
    decode_mean(sums8, u, m0, m1, m2);
    gridA0[0 * BVOXN + v] = m0;
    gridA0[1 * BVOXN + v] = m1;
    gridA0[2 * BVOXN + v] = m2;
    f32x4 m = {m0, m1, m2, 1.0f};
    meanex[v] = m;
}

// conv0: conv-frame (B,3,9,9,9)->(B,64,9,9,9), 3x3x3 pad 1, + bias.
// Output stored in RAW voxel-major layout conv0oT[v_raw][k_raw]:
// conv-frame (b,o,pos) lives at raw flat (b*64+o)*729+pos, i.e.
// k_raw = 2b + (o>>5), v_raw = (o&31)*729 + pos  (reference raw-view semantics).
__global__ __launch_bounds__(256) void k_conv0s(const float* gridA0, const float* w0t,
                                                const float* cb0, half_t* conv0oT) {
    __shared__ float slab[3 * 363];
    int b = blockIdx.x / 9, d = blockIdx.x % 9;
    int t = threadIdx.x;
    for (int s = t; s < 3 * 363; s += 256) {
        int i = s / 363, rr = s % 363;
        int zz = rr / 121, p = rr % 121;
        int ph = p / 11, pw = p % 11;
        int z = d + zz - 1, hh = ph - 1, ww = pw - 1;
        float v = 0.0f;
        if ((unsigned)z < 9u && (unsigned)hh < 9u && (unsigned)ww < 9u)
            v = gridA0[b * 2187 + i * 729 + z * 81 + hh * 9 + ww];
        slab[s] = v;
    }
    __syncthreads();

    int og = t >> 5, l = t & 31;
    int hw[3], hj[3], wj[3];
    bool valid[3];
    #pragma unroll
    for (int j = 0; j < 3; ++j) {
        int q = l + 32 * j;
        valid[j] = q < 81;
        int qc = q < 81 ? q : 80;
        hw[j] = q; hj[j] = qc / 9; wj[j] = qc % 9;
    }
    float acc[8][3];
    #pragma unroll
    for (int oj = 0; oj < 8; ++oj) {
        float bv = cb0[og * 8 + oj];
        acc[oj][0] = bv; acc[oj][1] = bv; acc[oj][2] = bv;
    }

    for (int i = 0; i < 3; ++i) {
        const float* sb = slab + i * 363;
        const float* wb = w0t + (i * 27) * 64 + og * 8;
        for (int kd = 0; kd < 3; ++kd)
            for (int kh = 0; kh < 3; ++kh) {
                int ib0 = kd * 121 + (hj[0] + kh) * 11 + wj[0];
                int ib1 = kd * 121 + (hj[1] + kh) * 11 + wj[1];
                int ib2 = kd * 121 + (hj[2] + kh) * 11 + wj[2];
                #pragma unroll
                for (int kw = 0; kw < 3; ++kw) {
                    int tap = kd * 9 + kh * 3 + kw;
                    const float4* w4 = reinterpret_cast<const float4*>(wb + tap * 64);
                    float4 wA = w4[0];
                    float4 wB = w4[1];
                    float in0 = sb[ib0 + kw];
                    float in1 = sb[ib1 + kw];
                    float in2 = sb[ib2 + kw];
                    acc[0][0] += wA.x * in0; acc[0][1] += wA.x * in1; acc[0][2] += wA.x * in2;
                    acc[1][0] += wA.y * in0; acc[1][1] += wA.y * in1; acc[1][2] += wA.y * in2;
                    acc[2][0] += wA.z * in0; acc[2][1] += wA.z * in1; acc[2][2] += wA.z * in2;
                    acc[3][0] += wA.w * in0; acc[3][1] += wA.w * in1; acc[3][2] += wA.w * in2;
                    acc[4][0] += wB.x * in0; acc[4][1] += wB.x * in1; acc[4][2] += wB.x * in2;
                    acc[5][0] += wB.y * in0; acc[5][1] += wB.y * in1; acc[5][2] += wB.y * in2;
                    acc[6][0] += wB.z * in0; acc[6][1] += wB.z * in1; acc[6][2] += wB.z * in2;
                    acc[7][0] += wB.w * in0; acc[7][1] += wB.w * in1; acc[7][2] += wB.w * in2;
                }
            }
    }

    #pragma unroll
    for (int oj = 0; oj < 8; ++oj) {
        int o = og * 8 + oj;
        int kraw = 2 * b + (o >> 5);
        int bvr = o & 31;
        #pragma unroll
        for (int j = 0; j < 3; ++j)
            if (valid[j])
                conv0oT[(bvr * 729 + d * 81 + hw[j]) * 64 + kraw] =
                    (half_t)acc[oj][j];
    }
}

// grid1 GATHER (replaces the scattered-write scatter1): one wave per conv-frame
// row (b',pos); lane ch reads raw (c = 2b'+(ch>>5), v = (ch&31)*729+pos) from
// the L2-resident meanex/conv0oT tables and writes the 128B gridTc row
// coalesced. Uncovered voxels (flag==0) -> 0, matching the reference grid.
__global__ __launch_bounds__(256) void k_grid1(const f32x4* __restrict__ meanex,
                                               const half_t* __restrict__ conv0oT,
                                               const float* __restrict__ l0w,
                                               const float* __restrict__ l0b,
                                               half_t* __restrict__ gridTc) {
    int r = blockIdx.x * 4 + (threadIdx.x >> 6);   // r = b'*729 + pos
    int ch = threadIdx.x & 63;
    int bp = r / 729, pos = r % 729;
    int c = 2 * bp + (ch >> 5);
    int v = (ch & 31) * 729 + pos;
    f32x4 m = meanex[v];
    float val = 0.0f;
    if (m[3] != 0.0f)
        val = l0b[c] + m[0] * l0w[c] + m[1] * l0w[64 + c] + m[2] * l0w[128 + c] +
              (float)conv0oT[v * 64 + c];
    gridTc[r * 64 + ch] = (half_t)val;
}

// conv1 via MFMA in the conv frame. Per block: one (b', z, N-half).
// M = 81 spatial (pad 96) over 6 waves, K = 27 taps x 64 ch, N = 32 outputs.
// Epilogue maps conv-frame (b', o', pos) to raw G[(o'&31)*729+pos][2b'+nh].
// LDS slab row stride 72 halfs (144 B): 4 banks mod 32 -> 2-way alias only (free).
__global__ __launch_bounds__(384) void k_conv1m(const half_t* __restrict__ gridTc,
                                                const half_t* __restrict__ Wt,
                                                const float* __restrict__ cb1,
                                                bf16* __restrict__ G) {
    __shared__ __align__(16) half_t slab[363 * 72];
    int bid = blockIdx.x;
    int nh = bid & 1;
    int t2 = bid >> 1;
    int b = t2 / 9, z = t2 % 9;
    int tid = threadIdx.x;

    // stage 3x11x11 halo window (conv-frame), channel-contiguous, zero-padded
    for (int s = tid; s < 2904; s += 384) {
        int pos = s >> 3, ic = s & 7;
        int zz = pos / 121, rr = pos % 121;
        int ph = rr / 11, pw = rr % 11;
        int zi = z + zz - 1, yi = ph - 1, xi = pw - 1;
        half8 v;
        #pragma unroll
        for (int j = 0; j < 8; ++j) v[j] = (half_t)0.f;
        if ((unsigned)zi < 9u && (unsigned)yi < 9u && (unsigned)xi < 9u)
            v = *(const half8*)&gridTc[(b * 729 + zi * 81 + yi * 9 + xi) * 64 + ic * 8];
        *(half8*)&slab[pos * 72 + ic * 8] = v;
    }
    __syncthreads();

    int w = tid >> 6;              // wave id = M-tile
    int l = tid & 63;
    int m16 = l & 15, kb = l >> 4;
    int qbase = w * 16;
    int qa = qbase + m16; if (qa > 80) qa = 80;   // clamp pad rows (not stored)
    int ya = qa / 9, xa = qa % 9;
    int laneA = (ya * 11 + xa) * 72 + kb * 8;
    int o0 = nh * 32 + m16;        // conv-frame output channel (acc0); acc1 = +16
    f32x4 acc0 = {0.f, 0.f, 0.f, 0.f};
    f32x4 acc1 = {0.f, 0.f, 0.f, 0.f};

    const half_t* wbase = Wt + (o0 * 64 + kb * 8);

    #pragma unroll
    for (int kd = 0; kd < 3; ++kd)
      #pragma unroll
      for (int kh = 0; kh < 3; ++kh)
        #pragma unroll
        for (int kw = 0; kw < 3; ++kw) {
            int tap = kd * 9 + kh * 3 + kw;
            int sb = laneA + (kd * 121 + kh * 11 + kw) * 72;
            const half_t* wt = wbase + tap * 4096;
            #pragma unroll
            for (int is = 0; is < 2; ++is) {
                half8 a  = *(const half8*)&slab[sb + is * 32];
                half8 b0 = *(const half8*)&wt[is * 32];
                half8 b1 = *(const half8*)&wt[1024 + is * 32];
                acc0 = __builtin_amdgcn_mfma_f32_16x16x32_f16(a, b0, acc0, 0, 0, 0);
                acc1 = __builtin_amdgcn_mfma_f32_16x16x32_f16(a, b1, acc1, 0, 0, 0);
            }
        }

    // D: col = lane&15 -> conv channel o0 (+16), row = kb*4+r -> spatial q.
    // Raw remap: v = (o'&31)*729 + z*81 + q, c = 2b'+nh; bias is conv-frame.
    float c0 = cb1[o0], c1 = cb1[o0 + 16];
    int cG = 2 * b + nh;
    int vb0 = m16 * 729 + z * 81;          // (o0 & 31) = m16
    int vb1 = (m16 + 16) * 729 + z * 81;   // ((o0+16) & 31) = m16+16
    #pragma unroll
    for (int r = 0; r < 4; ++r) {
        int q = qbase + kb * 4 + r;
        if (q < 81) {
            G[(vb0 + q) * 64 + cG] = __float2bfloat16(acc0[r] + c0);
            G[(vb1 + q) * 64 + cG] = __float2bfloat16(acc1[r] + c1);
        }
    }
}

// G[v][c] += sum_k conv0oT[v][k] * L1[k][c]  (lin1 term of G, raw frame).
// B operand = Wt tap 27 = L1^T[c][k]. One wave: 16 v-rows x 64 c.
__global__ __launch_bounds__(256) void k_G2(const half_t* __restrict__ conv0oT,
                                            const half_t* __restrict__ Wt,
                                            bf16* __restrict__ G) {
    int wid = (blockIdx.x * 256 + threadIdx.x) >> 6;
    int v0 = wid * 16;
    if (v0 >= BVOXN) return;
    int l = threadIdx.x & 63;
    int m16 = l & 15, kb = l >> 4;
    const half_t* wt27 = Wt + 27 * 4096;
    f32x4 acc[4];
    #pragma unroll
    for (int ct = 0; ct < 4; ++ct) acc[ct] = {0.f, 0.f, 0.f, 0.f};
    const half_t* ap = conv0oT + (v0 + m16) * 64 + kb * 8;
    #pragma unroll
    for (int is = 0; is < 2; ++is) {
        half8 a = *(const half8*)&ap[is * 32];
        #pragma unroll
        for (int ct = 0; ct < 4; ++ct) {
            half8 bf = *(const half8*)&wt27[(ct * 16 + m16) * 64 + kb * 8 + is * 32];
            acc[ct] = __builtin_amdgcn_mfma_f32_16x16x32_f16(a, bf, acc[ct], 0, 0, 0);
        }
    }
    #pragma unroll
    for (int ct = 0; ct < 4; ++ct)
        #pragma unroll
        for (int r = 0; r < 4; ++r) {
            int v = v0 + kb * 4 + r;
            int c = ct * 16 + m16;
            int idx = v * 64 + c;
            G[idx] = __float2bfloat16(b2f(G[idx]) + acc[ct][r]);
        }
}

__device__ __forceinline__ unsigned short f2bf_raw(float f) {
    bf16 h = __float2bfloat16(f);
    unsigned short u;
    __builtin_memcpy(&u, &h, 2);
    return u;
}

// out[i][c8..c8+7] = x[i]@Wc + bvec + G[cnc[i]]  — 8 channels per thread:
// ushort8 G load (16B, 8 lanes cover a 128B G row), 2x float4 stores.
__global__ __launch_bounds__(256) void k_out(const void* x, const int* cnc,
                                             const float* Wc, const float* bvec,
                                             const bf16* G, const int* flag,
                                             void* out, int N) {
    int t = blockIdx.x * 256 + threadIdx.x;
    int i = t >> 3;
    if (i >= N) return;
    int c8 = (t & 7) * 8;
    int isf = *flag;
    int v = cnc[i];
    float x0 = ldf(x, 3 * i + 0, isf);
    float x1 = ldf(x, 3 * i + 1, isf);
    float x2 = ldf(x, 3 * i + 2, isf);
    us8 g = *(const us8*)&G[v * 64 + c8];
    f32x4 w0a = *(const f32x4*)&Wc[c8];
    f32x4 w0b = *(const f32x4*)&Wc[c8 + 4];
    f32x4 w1a = *(const f32x4*)&Wc[64 + c8];
    f32x4 w1b = *(const f32x4*)&Wc[64 + c8 + 4];
    f32x4 w2a = *(const f32x4*)&Wc[128 + c8];
    f32x4 w2b = *(const f32x4*)&Wc[128 + c8 + 4];
    f32x4 bva = *(const f32x4*)&bvec[c8];
    f32x4 bvb = *(const f32x4*)&bvec[c8 + 4];
    f32x4 ra, rb;
    #pragma unroll
    for (int j = 0; j < 4; ++j) {
        float gfa = __uint_as_float((unsigned)g[j] << 16);
        float gfb = __uint_as_float((unsigned)g[j + 4] << 16);
        ra[j] = bva[j] + x0 * w0a[j] + x1 * w1a[j] + x2 * w2a[j] + gfa;
        rb[j] = bvb[j] + x0 * w0b[j] + x1 * w1b[j] + x2 * w2b[j] + gfb;
    }
    size_t oi = (size_t)i * 64 + c8;
    if (isf) {
        *(f32x4*)((float*)out + oi) = ra;
        *(f32x4*)((float*)out + oi + 4) = rb;
    } else {
        us8 h;
        #pragma unroll
        for (int j = 0; j < 4; ++j) {
            h[j] = f2bf_raw(ra[j]);
            h[j + 4] = f2bf_raw(rb[j]);
        }
        *(us8*)((bf16*)out + oi) = h;
    }
}

// ---------------------------------------------------------------------------
extern "C" void kernel_launch(void* const* d_in, const int* in_sizes, int n_in,
                              void* d_out, int out_size, void* d_ws, size_t ws_size,
                              hipStream_t stream) {
    const void* x       = d_in[0];
    const void* lin0_w  = d_in[1];
    const void* lin0_b  = d_in[2];
    const void* conv0_w = d_in[3];
    const void* conv0_b = d_in[4];
    const void* lin1_w  = d_in[5];
    const void* lin1_b  = d_in[6];
    const void* conv1_w = d_in[7];
    const void* conv1_b = d_in[8];
    const void* linf_w  = d_in[9];
    const void* linf_b  = d_in[10];
    const int* consec   = (const int*)d_in[11];
    const int* cnc      = (const int*)d_in[12];
    const int* unc      = (const int*)d_in[13];

    int N = in_sizes[0] / 3;
    int U = in_sizes[13];

    float* ws   = (float*)d_ws;
    int*   flag = (int*)d_ws;
    unsigned long long* sums8 = (unsigned long long*)(ws + OFF_SUMS);
    float*  gridA0  = ws + OFF_GA0;
    f32x4*  meanex  = (f32x4*)(ws + OFF_MEX);
    half_t* gridTc  = (half_t*)(ws + OFF_GT);
    half_t* conv0oT = (half_t*)(ws + OFF_C0T);
    half_t* Wt      = (half_t*)(ws + OFF_WT);
    float*  Wc      = ws + OFF_WC;
    float*  bvec    = ws + OFF_BVEC;
    bf16*   G       = (bf16*)(ws + OFF_G);

    // zero sums8 + gridA0 + meanex (contiguous; gridTc is fully written now)
    hipMemsetAsync((char*)d_ws + (size_t)OFF_SUMS * 4, 0,
                   (size_t)(OFF_GT - OFF_SUMS) * 4, stream);

    k_probe<<<1, 256, 0, stream>>>(lin1_w, flag);
    int NA = (N + 255) / 256;
    int SB = (SETUP_N + 255) / 256 + 1;
    k_sa<<<NA + SB, 256, 0, stream>>>(x, consec, N, NA,
        lin0_w, lin0_b, conv0_w, conv0_b, lin1_w, lin1_b, conv1_w, conv1_b,
        linf_w, linf_b, flag, ws, Wt, Wc, bvec, sums8);
    k_scatter0<<<(U + 255) / 256, 256, 0, stream>>>(sums8, unc, gridA0, meanex, U);
    k_conv0s<<<288, 256, 0, stream>>>(gridA0, ws + OFF_W0, ws + OFF_CB0, conv0oT);
    k_grid1<<<BVOXN / 4, 256, 0, stream>>>(meanex, conv0oT, ws + OFF_L0W,
                                           ws + OFF_B0, gridTc);
    k_conv1m<<<576, 384, 0, stream>>>(gridTc, Wt, ws + OFF_CB1, G);
    k_G2<<<(BVOXN / 16 * 64 + 255) / 256, 256, 0, stream>>>(conv0oT, Wt, G);
    long long tot = (long long)N * 8;
    k_out<<<(int)((tot + 255) / 256), 256, 0, stream>>>(x, cnc, Wc, bvec, G, flag,
                                                        d_out, N);
}

// Round 6
// 526.474 us; speedup vs baseline: 1.4652x; 1.0379x over previous
//
#include <hip/hip_runtime.h>
#include <hip/hip_bf16.h>
#include <stdint.h>

typedef __hip_bfloat16 bf16;
typedef _Float16 half_t;
typedef _Float16 half8 __attribute__((ext_vector_type(8)));
typedef float f32x4 __attribute__((ext_vector_type(4)));
typedef unsigned short us8 __attribute__((ext_vector_type(8)));

#define BVOXN 23328   // B * 729, B = 32 (fixed by setup_inputs)

__device__ __forceinline__ float b2f(bf16 v) { return __bfloat162float(v); }

// ---- workspace layout (float offsets) -------------------------------------
#define OFF_L0W   64        // 192    lin0_w f32
#define OFF_B0    256       // 64     lin0_b
#define OFF_W0    320       // 5184   conv0_w transposed [i][tap][o]
#define OFF_CB0   5504      // 64     conv0_b
#define OFF_CB1   120320    // 64     conv1_b
#define OFF_SUMS  120640    // 93312  u64[46656]: packed per-cluster sums (zeroed)
#define OFF_GA0   213952    // 69984  conv0 input grid f32 (zeroed)
#define OFF_MEX   283936    // 93312  f32x4[23328] meanex[v]={m0,m1,m2,flag} (zeroed)
#define OFF_GT    377248    // 746496 slots = half[1492992] conv-frame grid1
#define OFF_C0T   1123744   // 746496 slots = half[1492992] conv0oT[v_raw][k] (raw)
#define OFF_WT    1870240   // 57344  slots = half[114688] Wt[28][o][i]; tap27 = L1^T
#define OFF_WC    1927584   // 192    folded point matrix
#define OFF_BVEC  1927776   // 64     folded bias
#define OFF_G     1927840   // 746496 slots = bf16[1492992] voxel table G[v_raw][c]
// end = 2674336 f32 = 10.7 MB

// fixed-point packing for cluster sums: e = round(v*2^20) + 2^23 (always >0)
#define FP_SCALE 1048576.0f
#define FP_BIAS  8388608

// ---------------------------------------------------------------------------
// Decide whether float inputs are f32 (flag=1) or bf16 (flag=0).
__global__ void k_probe(const void* lin1_w, int* flag) {
    __shared__ int cnt[256];
    int t = threadIdx.x;
    const bf16* p = (const bf16*)lin1_w;
    int c = 0;
    for (int j = t; j < 2048; j += 256) {
        float v = b2f(p[2 * j]);
        if (!(v == v) || fabsf(v) > 64.0f || (v != 0.0f && fabsf(v) < 1e-20f)) c++;
    }
    cnt[t] = c;
    __syncthreads();
    for (int s = 128; s > 0; s >>= 1) {
        if (t < s) cnt[t] += cnt[t + s];
        __syncthreads();
    }
    if (t == 0) *flag = (cnt[0] > 100) ? 1 : 0;
}

__device__ __forceinline__ float ldf(const void* p, int j, int isf) {
    return isf ? ((const float*)p)[j] : b2f(((const bf16*)p)[j]);
}

// Merged setup + accum (both depend only on flag).
// Blocks [0, NA): per-point cluster-sum atomics.
// Blocks [NA, NA+470): weight conversion + Wt pack.
// Block NA+470 (tid<64): folded point matrix Wc/bvec from raw inputs.
#define SETUP_N 120256
__global__ void k_sa(const void* x, const int* consec, int N, int NA,
                     const void* l0w, const void* l0b, const void* w0,
                     const void* cb0, const void* l1w, const void* l1b,
                     const void* w1, const void* cb1, const void* lfw,
                     const void* lfb, const int* flag, float* ws,
                     half_t* Wt, float* Wc, float* bvec,
                     unsigned long long* sums8) {
    int isf = *flag;
    int bid = blockIdx.x;
    if (bid < NA) {
        int i = bid * 256 + threadIdx.x;
        if (i >= N) return;
        int u = consec[i];
        float v0 = ldf(x, 3 * i + 0, isf);
        float v1 = ldf(x, 3 * i + 1, isf);
        float v2 = ldf(x, 3 * i + 2, isf);
        unsigned e0 = (unsigned)(__float2int_rn(v0 * FP_SCALE) + FP_BIAS);
        unsigned e1 = (unsigned)(__float2int_rn(v1 * FP_SCALE) + FP_BIAS);
        unsigned e2 = (unsigned)(__float2int_rn(v2 * FP_SCALE) + FP_BIAS);
        atomicAdd(&sums8[2 * u + 0], ((unsigned long long)e0 << 32) | e1);
        atomicAdd(&sums8[2 * u + 1], (1ull << 32) | e2);
        return;
    }
    int t = (bid - NA) * 256 + threadIdx.x;
    if (t < SETUP_N) {
        if (t < 5568) {
            const void* src;
            int j;
            float* dst;
            if (t < 192)       { src = l0w; j = t;         dst = ws + OFF_L0W + j; }
            else if (t < 256)  { src = l0b; j = t - 192;   dst = ws + 256 + (j = t - 192, j); }
            else if (t < 5440) {
                j = t - 256;                    // conv0_w [o][i][tap] -> [i][tap][o]
                int o = j / 81, r = j % 81, i = r / 27, tap = r % 27;
                src = w0;
                dst = ws + OFF_W0 + (i * 27 + tap) * 64 + o;
            }
            else if (t < 5504) { src = cb0; j = t - 5440;  dst = ws + OFF_CB0 + j; }
            else               { src = cb1; j = t - 5504;  dst = ws + OFF_CB1 + j; }
            if (t >= 192 && t < 256) { src = l0b; j = t - 192; dst = ws + OFF_B0 + j; }
            *dst = ldf(src, j, isf);
        } else {
            // Wt[tap][o][i] f16: taps 0..26 = conv1_w [o][i][tap]; tap27 = l1w^T
            int q = t - 5568;
            int tap = q >> 12;
            int r = q & 4095;
            int o = r >> 6, i = r & 63;
            float v;
            if (tap < 27) v = ldf(w1, (o * 64 + i) * 27 + tap, isf);
            else          v = ldf(l1w, i * 64 + o, isf);
            Wt[q] = (half_t)v;
        }
        return;
    }
    // prep block: Wc = lin0_w@lin1_w + linf_w; bvec = lin0_b@lin1_w + lin1_b + linf_b
    if (bid == NA + (SETUP_N + 255) / 256 && threadIdx.x < 64) {
        int c = threadIdx.x;
        float bv = ldf(l1b, c, isf) + ldf(lfb, c, isf);
        for (int k = 0; k < 64; ++k)
            bv += ldf(l0b, k, isf) * ldf(l1w, k * 64 + c, isf);
        bvec[c] = bv;
        for (int r = 0; r < 3; ++r) {
            float wv = ldf(lfw, r * 64 + c, isf);
            for (int k = 0; k < 64; ++k)
                wv += ldf(l0w, r * 64 + k, isf) * ldf(l1w, k * 64 + c, isf);
            Wc[r * 64 + c] = wv;
        }
    }
}

__device__ __forceinline__ void decode_mean(const unsigned long long* sums8, int u,
                                            float& m0, float& m1, float& m2) {
    unsigned long long S1 = sums8[2 * u + 0];
    unsigned long long S2 = sums8[2 * u + 1];
    double n = (double)(unsigned)(S2 >> 32);
    double k = 1.0 / (1048576.0 * n);
    double nb = n * 8388608.0;
    m0 = (float)(((double)(unsigned)(S1 >> 32) - nb) * k);
    m1 = (float)(((double)(unsigned)(S1 & 0xffffffffu) - nb) * k);
    m2 = (float)(((double)(unsigned)(S2 & 0xffffffffu) - nb) * k);
}

// Scatter means into conv0 input grid (flat [3, BVOXN] raw-view) AND the
// voxel-indexed meanex table {m0,m1,m2,flag} used by the grid1 gather.
__global__ void k_scatter0(const unsigned long long* sums8, const int* unc,
                           float* gridA0, f32x4* meanex, int U) {
    int u = blockIdx.x * 256 + threadIdx.x;
    if (u >= U) return;
    int v = unc[u];
    float m0, m1, m2;
    decode_mean(sums8, u, m0, m1, m2);
    gridA0[0 * BVOXN + v] = m0;
    gridA0[1 * BVOXN + v] = m1;
    gridA0[2 * BVOXN + v] = m2;
    f32x4 m = {m0, m1, m2, 1.0f};
    meanex[v] = m;
}

// conv0: conv-frame (B,3,9,9,9)->(B,64,9,9,9), 3x3x3 pad 1, + bias.
// Output stored in RAW voxel-major layout conv0oT[v_raw][k_raw]:
// conv-frame (b,o,pos) lives at raw flat (b*64+o)*729+pos, i.e.
// k_raw = 2b + (o>>5), v_raw = (o&31)*729 + pos  (reference raw-view semantics).
__global__ __launch_bounds__(256) void k_conv0s(const float* gridA0, const float* w0t,
                                                const float* cb0, half_t* conv0oT) {
    __shared__ float slab[3 * 363];
    int b = blockIdx.x / 9, d = blockIdx.x % 9;
    int t = threadIdx.x;
    for (int s = t; s < 3 * 363; s += 256) {
        int i = s / 363, rr = s % 363;
        int zz = rr / 121, p = rr % 121;
        int ph = p / 11, pw = p % 11;
        int z = d + zz - 1, hh = ph - 1, ww = pw - 1;
        float v = 0.0f;
        if ((unsigned)z < 9u && (unsigned)hh < 9u && (unsigned)ww < 9u)
            v = gridA0[b * 2187 + i * 729 + z * 81 + hh * 9 + ww];
        slab[s] = v;
    }
    __syncthreads();

    int og = t >> 5, l = t & 31;
    int hw[3], hj[3], wj[3];
    bool valid[3];
    #pragma unroll
    for (int j = 0; j < 3; ++j) {
        int q = l + 32 * j;
        valid[j] = q < 81;
        int qc = q < 81 ? q : 80;
        hw[j] = q; hj[j] = qc / 9; wj[j] = qc % 9;
    }
    float acc[8][3];
    #pragma unroll
    for (int oj = 0; oj < 8; ++oj) {
        float bv = cb0[og * 8 + oj];
        acc[oj][0] = bv; acc[oj][1] = bv; acc[oj][2] = bv;
    }

    for (int i = 0; i < 3; ++i) {
        const float* sb = slab + i * 363;
        const float* wb = w0t + (i * 27) * 64 + og * 8;
        for (int kd = 0; kd < 3; ++kd)
            for (int kh = 0; kh < 3; ++kh) {
                int ib0 = kd * 121 + (hj[0] + kh) * 11 + wj[0];
                int ib1 = kd * 121 + (hj[1] + kh) * 11 + wj[1];
                int ib2 = kd * 121 + (hj[2] + kh) * 11 + wj[2];
                #pragma unroll
                for (int kw = 0; kw < 3; ++kw) {
                    int tap = kd * 9 + kh * 3 + kw;
                    const float4* w4 = reinterpret_cast<const float4*>(wb + tap * 64);
                    float4 wA = w4[0];
                    float4 wB = w4[1];
                    float in0 = sb[ib0 + kw];
                    float in1 = sb[ib1 + kw];
                    float in2 = sb[ib2 + kw];
                    acc[0][0] += wA.x * in0; acc[0][1] += wA.x * in1; acc[0][2] += wA.x * in2;
                    acc[1][0] += wA.y * in0; acc[1][1] += wA.y * in1; acc[1][2] += wA.y * in2;
                    acc[2][0] += wA.z * in0; acc[2][1] += wA.z * in1; acc[2][2] += wA.z * in2;
                    acc[3][0] += wA.w * in0; acc[3][1] += wA.w * in1; acc[3][2] += wA.w * in2;
                    acc[4][0] += wB.x * in0; acc[4][1] += wB.x * in1; acc[4][2] += wB.x * in2;
                    acc[5][0] += wB.y * in0; acc[5][1] += wB.y * in1; acc[5][2] += wB.y * in2;
                    acc[6][0] += wB.z * in0; acc[6][1] += wB.z * in1; acc[6][2] += wB.z * in2;
                    acc[7][0] += wB.w * in0; acc[7][1] += wB.w * in1; acc[7][2] += wB.w * in2;
                }
            }
    }

    #pragma unroll
    for (int oj = 0; oj < 8; ++oj) {
        int o = og * 8 + oj;
        int kraw = 2 * b + (o >> 5);
        int bvr = o & 31;
        #pragma unroll
        for (int j = 0; j < 3; ++j)
            if (valid[j])
                conv0oT[(bvr * 729 + d * 81 + hw[j]) * 64 + kraw] =
                    (half_t)acc[oj][j];
    }
}

// grid1 GATHER (replaces the scattered-write scatter1): one wave per conv-frame
// row (b',pos); lane ch reads raw (c = 2b'+(ch>>5), v = (ch&31)*729+pos) from
// the L2-resident meanex/conv0oT tables and writes the 128B gridTc row
// coalesced. Uncovered voxels (flag==0) -> 0, matching the reference grid.
__global__ __launch_bounds__(256) void k_grid1(const f32x4* __restrict__ meanex,
                                               const half_t* __restrict__ conv0oT,
                                               const float* __restrict__ l0w,
                                               const float* __restrict__ l0b,
                                               half_t* __restrict__ gridTc) {
    int r = blockIdx.x * 4 + (threadIdx.x >> 6);   // r = b'*729 + pos
    int ch = threadIdx.x & 63;
    int bp = r / 729, pos = r % 729;
    int c = 2 * bp + (ch >> 5);
    int v = (ch & 31) * 729 + pos;
    f32x4 m = meanex[v];
    float val = 0.0f;
    if (m[3] != 0.0f)
        val = l0b[c] + m[0] * l0w[c] + m[1] * l0w[64 + c] + m[2] * l0w[128 + c] +
              (float)conv0oT[v * 64 + c];
    gridTc[r * 64 + ch] = (half_t)val;
}

// conv1 via MFMA in the conv frame. Per block: one (b', z, N-half).
// M = 81 spatial (pad 96) over 6 waves, K = 27 taps x 64 ch, N = 32 outputs.
// Epilogue maps conv-frame (b', o', pos) to raw G[(o'&31)*729+pos][2b'+nh].
// LDS slab row stride 72 halfs (144 B): 4 banks mod 32 -> 2-way alias only (free).
__global__ __launch_bounds__(384) void k_conv1m(const half_t* __restrict__ gridTc,
                                                const half_t* __restrict__ Wt,
                                                const float* __restrict__ cb1,
                                                bf16* __restrict__ G) {
    __shared__ __align__(16) half_t slab[363 * 72];
    int bid = blockIdx.x;
    int nh = bid & 1;
    int t2 = bid >> 1;
    int b = t2 / 9, z = t2 % 9;
    int tid = threadIdx.x;

    // stage 3x11x11 halo window (conv-frame), channel-contiguous, zero-padded
    for (int s = tid; s < 2904; s += 384) {
        int pos = s >> 3, ic = s & 7;
        int zz = pos / 121, rr = pos % 121;
        int ph = rr / 11, pw = rr % 11;
        int zi = z + zz - 1, yi = ph - 1, xi = pw - 1;
        half8 v;
        #pragma unroll
        for (int j = 0; j < 8; ++j) v[j] = (half_t)0.f;
        if ((unsigned)zi < 9u && (unsigned)yi < 9u && (unsigned)xi < 9u)
            v = *(const half8*)&gridTc[(b * 729 + zi * 81 + yi * 9 + xi) * 64 + ic * 8];
        *(half8*)&slab[pos * 72 + ic * 8] = v;
    }
    __syncthreads();

    int w = tid >> 6;              // wave id = M-tile
    int l = tid & 63;
    int m16 = l & 15, kb = l >> 4;
    int qbase = w * 16;
    int qa = qbase + m16; if (qa > 80) qa = 80;   // clamp pad rows (not stored)
    int ya = qa / 9, xa = qa % 9;
    int laneA = (ya * 11 + xa) * 72 + kb * 8;
    int o0 = nh * 32 + m16;        // conv-frame output channel (acc0); acc1 = +16
    f32x4 acc0 = {0.f, 0.f, 0.f, 0.f};
    f32x4 acc1 = {0.f, 0.f, 0.f, 0.f};

    const half_t* wbase = Wt + (o0 * 64 + kb * 8);

    #pragma unroll
    for (int kd = 0; kd < 3; ++kd)
      #pragma unroll
      for (int kh = 0; kh < 3; ++kh)
        #pragma unroll
        for (int kw = 0; kw < 3; ++kw) {
            int tap = kd * 9 + kh * 3 + kw;
            int sb = laneA + (kd * 121 + kh * 11 + kw) * 72;
            const half_t* wt = wbase + tap * 4096;
            #pragma unroll
            for (int is = 0; is < 2; ++is) {
                half8 a  = *(const half8*)&slab[sb + is * 32];
                half8 b0 = *(const half8*)&wt[is * 32];
                half8 b1 = *(const half8*)&wt[1024 + is * 32];
                acc0 = __builtin_amdgcn_mfma_f32_16x16x32_f16(a, b0, acc0, 0, 0, 0);
                acc1 = __builtin_amdgcn_mfma_f32_16x16x32_f16(a, b1, acc1, 0, 0, 0);
            }
        }

    // D: col = lane&15 -> conv channel o0 (+16), row = kb*4+r -> spatial q.
    // Raw remap: v = (o'&31)*729 + z*81 + q, c = 2b'+nh; bias is conv-frame.
    float c0 = cb1[o0], c1 = cb1[o0 + 16];
    int cG = 2 * b + nh;
    int vb0 = m16 * 729 + z * 81;          // (o0 & 31) = m16
    int vb1 = (m16 + 16) * 729 + z * 81;   // ((o0+16) & 31) = m16+16
    #pragma unroll
    for (int r = 0; r < 4; ++r) {
        int q = qbase + kb * 4 + r;
        if (q < 81) {
            G[(vb0 + q) * 64 + cG] = __float2bfloat16(acc0[r] + c0);
            G[(vb1 + q) * 64 + cG] = __float2bfloat16(acc1[r] + c1);
        }
    }
}

// G[v][c] += sum_k conv0oT[v][k] * L1[k][c]  (lin1 term of G, raw frame).
// B operand = Wt tap 27 = L1^T[c][k]. One wave: 16 v-rows x 64 c.
__global__ __launch_bounds__(256) void k_G2(const half_t* __restrict__ conv0oT,
                                            const half_t* __restrict__ Wt,
                                            bf16* __restrict__ G) {
    int wid = (blockIdx.x * 256 + threadIdx.x) >> 6;
    int v0 = wid * 16;
    if (v0 >= BVOXN) return;
    int l = threadIdx.x & 63;
    int m16 = l & 15, kb = l >> 4;
    const half_t* wt27 = Wt + 27 * 4096;
    f32x4 acc[4];
    #pragma unroll
    for (int ct = 0; ct < 4; ++ct) acc[ct] = {0.f, 0.f, 0.f, 0.f};
    const half_t* ap = conv0oT + (v0 + m16) * 64 + kb * 8;
    #pragma unroll
    for (int is = 0; is < 2; ++is) {
        half8 a = *(const half8*)&ap[is * 32];
        #pragma unroll
        for (int ct = 0; ct < 4; ++ct) {
            half8 bf = *(const half8*)&wt27[(ct * 16 + m16) * 64 + kb * 8 + is * 32];
            acc[ct] = __builtin_amdgcn_mfma_f32_16x16x32_f16(a, bf, acc[ct], 0, 0, 0);
        }
    }
    #pragma unroll
    for (int ct = 0; ct < 4; ++ct)
        #pragma unroll
        for (int r = 0; r < 4; ++r) {
            int v = v0 + kb * 4 + r;
            int c = ct * 16 + m16;
            int idx = v * 64 + c;
            G[idx] = __float2bfloat16(b2f(G[idx]) + acc[ct][r]);
        }
}

__device__ __forceinline__ unsigned short f2bf_raw(float f) {
    bf16 h = __float2bfloat16(f);
    unsigned short u;
    __builtin_memcpy(&u, &h, 2);
    return u;
}

// out[i][c8..c8+7] = x[i]@Wc + bvec + G[cnc[i]]. Grid-stride; per-thread c8
// fixed -> Wc/bvec hoisted to registers. Within each 8-lane point-group,
// lanes 0-2 load x components, lane 3 loads cnc; __shfl broadcasts (cuts
// per-point scalar loads 32 -> 4; kernel was VMEM-issue-bound).
__global__ __launch_bounds__(256) void k_out(const void* x, const int* cnc,
                                             const float* Wc, const float* bvec,
                                             const bf16* G, const int* flag,
                                             void* out, int N, int nthreads) {
    int isf = *flag;
    int tid = blockIdx.x * 256 + threadIdx.x;
    int lane = threadIdx.x & 63;
    int sub = lane & 7;
    int gb = lane & 56;
    int c8 = sub * 8;
    f32x4 w0a = *(const f32x4*)&Wc[c8];
    f32x4 w0b = *(const f32x4*)&Wc[c8 + 4];
    f32x4 w1a = *(const f32x4*)&Wc[64 + c8];
    f32x4 w1b = *(const f32x4*)&Wc[64 + c8 + 4];
    f32x4 w2a = *(const f32x4*)&Wc[128 + c8];
    f32x4 w2b = *(const f32x4*)&Wc[128 + c8 + 4];
    f32x4 bva = *(const f32x4*)&bvec[c8];
    f32x4 bvb = *(const f32x4*)&bvec[c8 + 4];
    long long tot = (long long)N * 8;
    for (long long t = tid; t < tot; t += nthreads) {
        int i = (int)(t >> 3);
        float xv = 0.0f;
        int cv = 0;
        if (sub < 3) xv = ldf(x, 3 * i + sub, isf);
        else if (sub == 3) cv = cnc[i];
        float x0 = __shfl(xv, gb + 0);
        float x1 = __shfl(xv, gb + 1);
        float x2 = __shfl(xv, gb + 2);
        int v = __shfl(cv, gb + 3);
        us8 g = *(const us8*)&G[(size_t)v * 64 + c8];
        f32x4 ra, rb;
        #pragma unroll
        for (int j = 0; j < 4; ++j) {
            float gfa = __uint_as_float((unsigned)g[j] << 16);
            float gfb = __uint_as_float((unsigned)g[j + 4] << 16);
            ra[j] = bva[j] + x0 * w0a[j] + x1 * w1a[j] + x2 * w2a[j] + gfa;
            rb[j] = bvb[j] + x0 * w0b[j] + x1 * w1b[j] + x2 * w2b[j] + gfb;
        }
        size_t oi = (size_t)i * 64 + c8;
        if (isf) {
            *(f32x4*)((float*)out + oi) = ra;
            *(f32x4*)((float*)out + oi + 4) = rb;
        } else {
            us8 h;
            #pragma unroll
            for (int j = 0; j < 4; ++j) {
                h[j] = f2bf_raw(ra[j]);
                h[j + 4] = f2bf_raw(rb[j]);
            }
            *(us8*)((bf16*)out + oi) = h;
        }
    }
}

// ---------------------------------------------------------------------------
extern "C" void kernel_launch(void* const* d_in, const int* in_sizes, int n_in,
                              void* d_out, int out_size, void* d_ws, size_t ws_size,
                              hipStream_t stream) {
    const void* x       = d_in[0];
    const void* lin0_w  = d_in[1];
    const void* lin0_b  = d_in[2];
    const void* conv0_w = d_in[3];
    const void* conv0_b = d_in[4];
    const void* lin1_w  = d_in[5];
    const void* lin1_b  = d_in[6];
    const void* conv1_w = d_in[7];
    const void* conv1_b = d_in[8];
    const void* linf_w  = d_in[9];
    const void* linf_b  = d_in[10];
    const int* consec   = (const int*)d_in[11];
    const int* cnc      = (const int*)d_in[12];
    const int* unc      = (const int*)d_in[13];

    int N = in_sizes[0] / 3;
    int U = in_sizes[13];

    float* ws   = (float*)d_ws;
    int*   flag = (int*)d_ws;
    unsigned long long* sums8 = (unsigned long long*)(ws + OFF_SUMS);
    float*  gridA0  = ws + OFF_GA0;
    f32x4*  meanex  = (f32x4*)(ws + OFF_MEX);
    half_t* gridTc  = (half_t*)(ws + OFF_GT);
    half_t* conv0oT = (half_t*)(ws + OFF_C0T);
    half_t* Wt      = (half_t*)(ws + OFF_WT);
    float*  Wc      = ws + OFF_WC;
    float*  bvec    = ws + OFF_BVEC;
    bf16*   G       = (bf16*)(ws + OFF_G);

    // zero sums8 + gridA0 + meanex (contiguous; gridTc is fully written now)
    hipMemsetAsync((char*)d_ws + (size_t)OFF_SUMS * 4, 0,
                   (size_t)(OFF_GT - OFF_SUMS) * 4, stream);

    k_probe<<<1, 256, 0, stream>>>(lin1_w, flag);
    int NA = (N + 255) / 256;
    int SB = (SETUP_N + 255) / 256 + 1;
    k_sa<<<NA + SB, 256, 0, stream>>>(x, consec, N, NA,
        lin0_w, lin0_b, conv0_w, conv0_b, lin1_w, lin1_b, conv1_w, conv1_b,
        linf_w, linf_b, flag, ws, Wt, Wc, bvec, sums8);
    k_scatter0<<<(U + 255) / 256, 256, 0, stream>>>(sums8, unc, gridA0, meanex, U);
    k_conv0s<<<288, 256, 0, stream>>>(gridA0, ws + OFF_W0, ws + OFF_CB0, conv0oT);
    k_grid1<<<BVOXN / 4, 256, 0, stream>>>(meanex, conv0oT, ws + OFF_L0W,
                                           ws + OFF_B0, gridTc);
    k_conv1m<<<576, 384, 0, stream>>>(gridTc, Wt, ws + OFF_CB1, G);
    k_G2<<<(BVOXN / 16 * 64 + 255) / 256, 256, 0, stream>>>(conv0oT, Wt, G);
    long long tot8 = (long long)N * 8;
    int blocks = (int)((tot8 + 255) / 256);
    if (blocks > 2048) blocks = 2048;
    k_out<<<blocks, 256, 0, stream>>>(x, cnc, Wc, bvec, G, flag, d_out, N,
                                      blocks * 256);
}